// Round 2
// baseline (999.451 us; speedup 1.0000x reference)
//
#include <hip/hip_runtime.h>
#include <hip/hip_bf16.h>
#include <math.h>

// Problem constants (H=W=128 passed as inputs but fixed for this problem)
#define B_ 4
#define HH 128
#define WW 128
#define CC 256
#define LL (HH * WW)          // 16384
#define NROWS (B_ * LL)       // 65536
#define NREL 945              // (2*8-1)*(2*32-1)
#define SCALE 0.17677669529663687f  // 32^-0.5

// ---------------------------------------------------------------------------
// DynamicPosBias MLP: 945 rows x 2 branches, tiny. pos[br][rel][head]
// ---------------------------------------------------------------------------
__device__ inline void ln_relu8(float* v, const float* g, const float* b) {
    float m = 0.f;
#pragma unroll
    for (int j = 0; j < 8; j++) m += v[j];
    m *= 0.125f;
    float var = 0.f;
#pragma unroll
    for (int j = 0; j < 8; j++) { float d = v[j] - m; var += d * d; }
    var *= 0.125f;
    float inv = 1.0f / sqrtf(var + 1e-5f);
#pragma unroll
    for (int j = 0; j < 8; j++) {
        float xn = (v[j] - m) * inv * g[j] + b[j];
        v[j] = xn > 0.f ? xn : 0.f;
    }
}

__device__ inline void mat8x8(const float* in, float* out, const float* w, const float* bias) {
#pragma unroll
    for (int j = 0; j < 8; j++) {
        float s = bias[j];
#pragma unroll
        for (int i = 0; i < 8; i++) s = fmaf(in[i], w[i * 8 + j], s);
        out[j] = s;
    }
}

__global__ void pos_kernel(const float* __restrict__ pp_w, const float* __restrict__ pp_b,
                           const float* __restrict__ ln1_g, const float* __restrict__ ln1_b,
                           const float* __restrict__ l1_w, const float* __restrict__ l1_b,
                           const float* __restrict__ ln2_g, const float* __restrict__ ln2_b,
                           const float* __restrict__ l2_w, const float* __restrict__ l2_b,
                           const float* __restrict__ ln3_g, const float* __restrict__ ln3_b,
                           const float* __restrict__ l3_w, const float* __restrict__ l3_b,
                           float* __restrict__ pos) {
    const int br = blockIdx.x;
    const int Wsp = br ? 8 : 32;
    const int Hsp = br ? 32 : 8;
    const int W2 = 2 * Wsp - 1;
    const int nrel = (2 * Hsp - 1) * W2;  // 945 both branches
    for (int r = threadIdx.x; r < nrel; r += blockDim.x) {
        float dy = (float)(r / W2 - (Hsp - 1));
        float dx = (float)(r % W2 - (Wsp - 1));
        float p[8], t[8];
#pragma unroll
        for (int j = 0; j < 8; j++)
            p[j] = dy * pp_w[br * 16 + j] + dx * pp_w[br * 16 + 8 + j] + pp_b[br * 8 + j];
        ln_relu8(p, ln1_g + br * 8, ln1_b + br * 8);
        mat8x8(p, t, l1_w + br * 64, l1_b + br * 8);
        ln_relu8(t, ln2_g + br * 8, ln2_b + br * 8);
        mat8x8(t, p, l2_w + br * 64, l2_b + br * 8);
        ln_relu8(p, ln3_g + br * 8, ln3_b + br * 8);
#pragma unroll
        for (int j = 0; j < 4; j++) {
            float s = l3_b[br * 4 + j];
#pragma unroll
            for (int i = 0; i < 8; i++) s = fmaf(p[i], l3_w[br * 32 + i * 4 + j], s);
            pos[(br * NREL + r) * 4 + j] = s;
        }
    }
}

// Expand to T[br][h][m][n] so the attention m-loop reads the bias coalesced in n.
__global__ void rpb_kernel(const float* __restrict__ pos, float* __restrict__ T) {
    const int n = threadIdx.x;       // attention row (query)
    const int m = blockIdx.x;        // attention col (key)
    const int h = blockIdx.y;
    const int br = blockIdx.z;
    const int logW = br ? 3 : 5;
    const int Wsp = 1 << logW;
    const int Hsp = 256 >> logW;
    const int W2 = 2 * Wsp - 1;
    const int i_n = n >> logW, j_n = n & (Wsp - 1);
    const int i_m = m >> logW, j_m = m & (Wsp - 1);
    const int idx = (i_n - i_m + Hsp - 1) * W2 + (j_n - j_m + Wsp - 1);
    T[(((size_t)(br * 4 + h) * 256) + m) * 256 + n] = pos[(br * NREL + idx) * 4 + h];
}

// ---------------------------------------------------------------------------
// fp32 SGEMM: C[M x N] = A[M x K] * B[K x N] (+bias). 128x128 tile, BK=8,
// 256 threads, 8x8 micro-tile. Register prefetch of next K-slab.
// ---------------------------------------------------------------------------
__global__ __launch_bounds__(256) void sgemm128(const float* __restrict__ A,
                                                const float* __restrict__ B,
                                                float* __restrict__ C,
                                                int lda, int ldb, int ldc, int K,
                                                const float* __restrict__ bias) {
    __shared__ float As[8][128];  // As[k][m]
    __shared__ float Bs[8][128];  // Bs[k][n]
    const int tid = threadIdx.x;
    const int tx = tid & 15;
    const int ty = tid >> 4;
    const size_t blockM = (size_t)blockIdx.x * 128;
    const int blockN = blockIdx.y * 128;

    const int ar = tid >> 1;          // A row within tile
    const int ak = (tid & 1) * 4;     // A k-offset
    const int bk = tid >> 5;          // B k-row
    const int bc = (tid & 31) * 4;    // B col offset

    const float* Aptr = A + (blockM + ar) * lda + ak;
    const float* Bptr = B + (size_t)bk * ldb + blockN + bc;

    float acc[8][8];
#pragma unroll
    for (int i = 0; i < 8; i++)
#pragma unroll
        for (int j = 0; j < 8; j++) acc[i][j] = 0.f;

    float4 a_reg = *(const float4*)(Aptr);
    float4 b_reg = *(const float4*)(Bptr);

    for (int kb = 0; kb < K; kb += 8) {
        As[ak + 0][ar] = a_reg.x;
        As[ak + 1][ar] = a_reg.y;
        As[ak + 2][ar] = a_reg.z;
        As[ak + 3][ar] = a_reg.w;
        *(float4*)&Bs[bk][bc] = b_reg;
        __syncthreads();
        if (kb + 8 < K) {
            a_reg = *(const float4*)(Aptr + kb + 8);
            b_reg = *(const float4*)(Bptr + (size_t)(kb + 8) * ldb);
        }
#pragma unroll
        for (int k = 0; k < 8; k++) {
            float4 a0 = *(const float4*)&As[k][ty * 8];
            float4 a1 = *(const float4*)&As[k][ty * 8 + 4];
            float4 b0 = *(const float4*)&Bs[k][tx * 4];
            float4 b1 = *(const float4*)&Bs[k][tx * 4 + 64];
            float av[8] = {a0.x, a0.y, a0.z, a0.w, a1.x, a1.y, a1.z, a1.w};
            float bv[8] = {b0.x, b0.y, b0.z, b0.w, b1.x, b1.y, b1.z, b1.w};
#pragma unroll
            for (int i = 0; i < 8; i++)
#pragma unroll
                for (int j = 0; j < 8; j++) acc[i][j] = fmaf(av[i], bv[j], acc[i][j]);
        }
        __syncthreads();
    }

#pragma unroll
    for (int i = 0; i < 8; i++) {
        size_t row = blockM + ty * 8 + i;
        float4 r0, r1;
        r0.x = acc[i][0]; r0.y = acc[i][1]; r0.z = acc[i][2]; r0.w = acc[i][3];
        r1.x = acc[i][4]; r1.y = acc[i][5]; r1.z = acc[i][6]; r1.w = acc[i][7];
        if (bias) {
            r0.x += bias[blockN + tx * 4 + 0]; r0.y += bias[blockN + tx * 4 + 1];
            r0.z += bias[blockN + tx * 4 + 2]; r0.w += bias[blockN + tx * 4 + 3];
            r1.x += bias[blockN + 64 + tx * 4 + 0]; r1.y += bias[blockN + 64 + tx * 4 + 1];
            r1.z += bias[blockN + 64 + tx * 4 + 2]; r1.w += bias[blockN + 64 + tx * 4 + 3];
        }
        *(float4*)(C + row * ldc + blockN + tx * 4) = r0;
        *(float4*)(C + row * ldc + blockN + 64 + tx * 4) = r1;
    }
}

// ---------------------------------------------------------------------------
// Window attention, one block per (window, head, branch). N=256, hd=32.
// K,V staged in exactly 64 KB LDS; thread t owns query row t; single-pass
// softmax without max-subtraction (|s| <~ 1 by construction: 0.02-scale
// weights; mathematically identical to jax softmax).
// ---------------------------------------------------------------------------
__global__ __launch_bounds__(256) void attn_kernel(const float* __restrict__ qkv,
                                                   const float* __restrict__ T,
                                                   float* __restrict__ att) {
    __shared__ float Ks[256][32];
    __shared__ float Vs[256][32];
    const int tid = threadIdx.x;
    const int wi = blockIdx.x;   // 0..255 : b*64 + window
    const int h = blockIdx.y;    // 0..3
    const int br = blockIdx.z;   // 0..1
    const int logW = br ? 3 : 5;           // Wsp: 32 (br0), 8 (br1)
    const int Wsp = 1 << logW;
    const int Hsp = 256 >> logW;
    const int logNWx = br ? 4 : 2;         // nWx = 128/Wsp
    const int b = wi >> 6;
    const int win = wi & 63;
    const int wy = win >> logNWx;
    const int wx = win & ((1 << logNWx) - 1);
    const int ccol = br * 128 + h * 32;

    // stage K and V
#pragma unroll
    for (int it = 0; it < 8; ++it) {
        int n = it * 32 + (tid >> 3);
        int d4 = (tid & 7) * 4;
        int iy = n >> logW, ix = n & (Wsp - 1);
        size_t row = ((size_t)b * LL + (wy * Hsp + iy) * WW + wx * Wsp + ix) * 768;
        *(float4*)&Ks[n][d4] = *(const float4*)(qkv + row + 256 + ccol + d4);
        *(float4*)&Vs[n][d4] = *(const float4*)(qkv + row + 512 + ccol + d4);
    }

    // own Q row (pre-scaled)
    const int n0 = tid;
    const int iy0 = n0 >> logW, ix0 = n0 & (Wsp - 1);
    const size_t prow = (size_t)b * LL + (wy * Hsp + iy0) * WW + wx * Wsp + ix0;
    const float* qp = qkv + prow * 768 + ccol;
    float q[32];
#pragma unroll
    for (int d = 0; d < 32; d += 4) {
        float4 t4 = *(const float4*)(qp + d);
        q[d] = t4.x * SCALE; q[d + 1] = t4.y * SCALE;
        q[d + 2] = t4.z * SCALE; q[d + 3] = t4.w * SCALE;
    }
    __syncthreads();

    const float* Trow = T + (size_t)(br * 4 + h) * 65536 + n0;  // +m*256
    float o[32];
#pragma unroll
    for (int d = 0; d < 32; d++) o[d] = 0.f;
    float denom = 0.f;

#pragma unroll 2
    for (int m = 0; m < 256; ++m) {
        float s = Trow[(size_t)m * 256];
#pragma unroll
        for (int d = 0; d < 32; ++d) s = fmaf(q[d], Ks[m][d], s);
        float p = __expf(s);
        denom += p;
#pragma unroll
        for (int d = 0; d < 32; ++d) o[d] = fmaf(p, Vs[m][d], o[d]);
    }
    float inv = 1.0f / denom;
    float* op = att + prow * 256 + ccol;
#pragma unroll
    for (int d = 0; d < 32; d += 4) {
        float4 r;
        r.x = o[d] * inv; r.y = o[d + 1] * inv;
        r.z = o[d + 2] * inv; r.w = o[d + 3] * inv;
        *(float4*)(op + d) = r;
    }
}

// ---------------------------------------------------------------------------
// LePE: depthwise 3x3 (cross-correlation, zero pad) on V, += into att buffer.
// One block per pixel, thread = channel (coalesced in c).
// ---------------------------------------------------------------------------
__global__ __launch_bounds__(256) void lepe_kernel(const float* __restrict__ qkv,
                                                   const float* __restrict__ w_dw,
                                                   const float* __restrict__ b_dw,
                                                   float* __restrict__ att) {
    const int c = threadIdx.x;
    const int pix = blockIdx.x;      // b*16384 + y*128 + x
    const int bb = pix >> 14;
    const int y = (pix >> 7) & 127;
    const int x = pix & 127;
    float wloc[9];
#pragma unroll
    for (int j = 0; j < 9; j++) wloc[j] = w_dw[c * 9 + j];
    float acc = b_dw[c];
#pragma unroll
    for (int ky = 0; ky < 3; ky++) {
        int yy = y + ky - 1;
        if (yy < 0 || yy > 127) continue;
#pragma unroll
        for (int kx = 0; kx < 3; kx++) {
            int xx = x + kx - 1;
            if (xx < 0 || xx > 127) continue;
            acc = fmaf(qkv[(((size_t)bb << 14) + yy * 128 + xx) * 768 + 512 + c],
                       wloc[ky * 3 + kx], acc);
        }
    }
    att[((size_t)pix << 8) + c] += acc;
}

// ---------------------------------------------------------------------------
extern "C" void kernel_launch(void* const* d_in, const int* in_sizes, int n_in,
                              void* d_out, int out_size, void* d_ws, size_t ws_size,
                              hipStream_t stream) {
    const float* x     = (const float*)d_in[0];
    const float* w_qkv = (const float*)d_in[1];
    const float* w_proj= (const float*)d_in[2];
    const float* b_proj= (const float*)d_in[3];
    const float* w_dw  = (const float*)d_in[4];
    const float* b_dw  = (const float*)d_in[5];
    const float* pp_w  = (const float*)d_in[6];
    const float* pp_b  = (const float*)d_in[7];
    const float* ln1_g = (const float*)d_in[8];
    const float* ln1_b = (const float*)d_in[9];
    const float* l1_w  = (const float*)d_in[10];
    const float* l1_b  = (const float*)d_in[11];
    const float* ln2_g = (const float*)d_in[12];
    const float* ln2_b = (const float*)d_in[13];
    const float* l2_w  = (const float*)d_in[14];
    const float* l2_b  = (const float*)d_in[15];
    const float* ln3_g = (const float*)d_in[16];
    const float* ln3_b = (const float*)d_in[17];
    const float* l3_w  = (const float*)d_in[18];
    const float* l3_b  = (const float*)d_in[19];

    // Workspace layout (fp32 elements): tables first, then qkv. Total ~194 MiB.
    //  - attb (attention + LePE accumulator) lives in d_out (64 MiB, exactly out_size)
    //  - gemm2 writes into the dead qkv region, then D2D-copied to d_out
    float* pos  = (float*)d_ws;                 // 7,680 floats (945*4*2 padded)
    float* T    = pos + 7680;                   // 524,288 floats (2 MiB)
    float* qkv  = T + 524288;                   // 50,331,648 floats (192 MiB)
    float* attb = (float*)d_out;                // 16,777,216 floats (alias d_out)
    float* out2 = qkv;                          // alias: qkv dead after attn+lepe

    pos_kernel<<<2, 128, 0, stream>>>(pp_w, pp_b, ln1_g, ln1_b, l1_w, l1_b,
                                      ln2_g, ln2_b, l2_w, l2_b, ln3_g, ln3_b,
                                      l3_w, l3_b, pos);
    rpb_kernel<<<dim3(256, 4, 2), 256, 0, stream>>>(pos, T);
    // qkv = x @ w_qkv   (65536 x 256) * (256 x 768)
    sgemm128<<<dim3(NROWS / 128, 768 / 128), 256, 0, stream>>>(x, w_qkv, qkv,
                                                               256, 768, 768, 256, nullptr);
    // window attention (both branches, 4 heads each) -> writes every attb element
    attn_kernel<<<dim3(256, 4, 2), 256, 0, stream>>>(qkv, T, attb);
    // LePE += depthwise conv on V
    lepe_kernel<<<B_ * LL, 256, 0, stream>>>(qkv, w_dw, b_dw, attb);
    // out2 = attb @ w_proj + b_proj  (writes into dead qkv region)
    sgemm128<<<dim3(NROWS / 128, 256 / 128), 256, 0, stream>>>(attb, w_proj, out2,
                                                               256, 256, 256, 256, b_proj);
    // final result -> d_out
    hipMemcpyAsync(d_out, out2, (size_t)NROWS * 256 * sizeof(float),
                   hipMemcpyDeviceToDevice, stream);
}

// Round 3
// 761.773 us; speedup vs baseline: 1.3120x; 1.3120x over previous
//
#include <hip/hip_runtime.h>
#include <hip/hip_bf16.h>
#include <math.h>

// Problem constants (H=W=128 passed as inputs but fixed for this problem)
#define B_ 4
#define HH 128
#define WW 128
#define CC 256
#define LL (HH * WW)          // 16384
#define NROWS (B_ * LL)       // 65536
#define NREL 945              // (2*8-1)*(2*32-1)
#define SCALE 0.17677669529663687f  // 32^-0.5

typedef __attribute__((ext_vector_type(8))) short bhalf8;
typedef __attribute__((ext_vector_type(4))) float f32x4;

__device__ inline unsigned short f2bf(float f) {
    union { float f; unsigned u; } v; v.f = f;
    unsigned r = v.u + 0x7FFFu + ((v.u >> 16) & 1u);
    return (unsigned short)(r >> 16);
}

// ---------------------------------------------------------------------------
// DynamicPosBias MLP: 945 rows x 2 branches, tiny. pos[br][rel][head]
// ---------------------------------------------------------------------------
__device__ inline void ln_relu8(float* v, const float* g, const float* b) {
    float m = 0.f;
#pragma unroll
    for (int j = 0; j < 8; j++) m += v[j];
    m *= 0.125f;
    float var = 0.f;
#pragma unroll
    for (int j = 0; j < 8; j++) { float d = v[j] - m; var += d * d; }
    var *= 0.125f;
    float inv = 1.0f / sqrtf(var + 1e-5f);
#pragma unroll
    for (int j = 0; j < 8; j++) {
        float xn = (v[j] - m) * inv * g[j] + b[j];
        v[j] = xn > 0.f ? xn : 0.f;
    }
}

__device__ inline void mat8x8(const float* in, float* out, const float* w, const float* bias) {
#pragma unroll
    for (int j = 0; j < 8; j++) {
        float s = bias[j];
#pragma unroll
        for (int i = 0; i < 8; i++) s = fmaf(in[i], w[i * 8 + j], s);
        out[j] = s;
    }
}

__global__ void pos_kernel(const float* __restrict__ pp_w, const float* __restrict__ pp_b,
                           const float* __restrict__ ln1_g, const float* __restrict__ ln1_b,
                           const float* __restrict__ l1_w, const float* __restrict__ l1_b,
                           const float* __restrict__ ln2_g, const float* __restrict__ ln2_b,
                           const float* __restrict__ l2_w, const float* __restrict__ l2_b,
                           const float* __restrict__ ln3_g, const float* __restrict__ ln3_b,
                           const float* __restrict__ l3_w, const float* __restrict__ l3_b,
                           float* __restrict__ pos) {
    const int br = blockIdx.x;
    const int Wsp = br ? 8 : 32;
    const int Hsp = br ? 32 : 8;
    const int W2 = 2 * Wsp - 1;
    const int nrel = (2 * Hsp - 1) * W2;  // 945 both branches
    for (int r = threadIdx.x; r < nrel; r += blockDim.x) {
        float dy = (float)(r / W2 - (Hsp - 1));
        float dx = (float)(r % W2 - (Wsp - 1));
        float p[8], t[8];
#pragma unroll
        for (int j = 0; j < 8; j++)
            p[j] = dy * pp_w[br * 16 + j] + dx * pp_w[br * 16 + 8 + j] + pp_b[br * 8 + j];
        ln_relu8(p, ln1_g + br * 8, ln1_b + br * 8);
        mat8x8(p, t, l1_w + br * 64, l1_b + br * 8);
        ln_relu8(t, ln2_g + br * 8, ln2_b + br * 8);
        mat8x8(t, p, l2_w + br * 64, l2_b + br * 8);
        ln_relu8(p, ln3_g + br * 8, ln3_b + br * 8);
#pragma unroll
        for (int j = 0; j < 4; j++) {
            float s = l3_b[br * 4 + j];
#pragma unroll
            for (int i = 0; i < 8; i++) s = fmaf(p[i], l3_w[br * 32 + i * 4 + j], s);
            pos[(br * NREL + r) * 4 + j] = s;
        }
    }
}

// T2[br][h][n(query)][m(key)] — query-major so MFMA C-layout bias reads coalesce.
__global__ void rpb_kernel(const float* __restrict__ pos, float* __restrict__ T2) {
    const int m = threadIdx.x;       // key
    const int n = blockIdx.x;        // query
    const int h = blockIdx.y;
    const int br = blockIdx.z;
    const int logW = br ? 3 : 5;
    const int Wsp = 1 << logW;
    const int Hsp = 256 >> logW;
    const int W2 = 2 * Wsp - 1;
    const int i_n = n >> logW, j_n = n & (Wsp - 1);
    const int i_m = m >> logW, j_m = m & (Wsp - 1);
    const int idx = (i_n - i_m + Hsp - 1) * W2 + (j_n - j_m + Wsp - 1);
    T2[(((size_t)(br * 4 + h) * 256) + n) * 256 + m] = pos[(br * NREL + idx) * 4 + h];
}

// ---------------------------------------------------------------------------
// fp32 SGEMM: C[M x N] = A[M x K] * B[K x N] (+bias). 128x128 tile, BK=8,
// 256 threads, 8x8 micro-tile. Register prefetch of next K-slab.
// ---------------------------------------------------------------------------
__global__ __launch_bounds__(256) void sgemm128(const float* __restrict__ A,
                                                const float* __restrict__ B,
                                                float* __restrict__ C,
                                                int lda, int ldb, int ldc, int K,
                                                const float* __restrict__ bias) {
    __shared__ float As[8][128];  // As[k][m]
    __shared__ float Bs[8][128];  // Bs[k][n]
    const int tid = threadIdx.x;
    const int tx = tid & 15;
    const int ty = tid >> 4;
    const size_t blockM = (size_t)blockIdx.x * 128;
    const int blockN = blockIdx.y * 128;

    const int ar = tid >> 1;          // A row within tile
    const int ak = (tid & 1) * 4;     // A k-offset
    const int bk = tid >> 5;          // B k-row
    const int bc = (tid & 31) * 4;    // B col offset

    const float* Aptr = A + (blockM + ar) * lda + ak;
    const float* Bptr = B + (size_t)bk * ldb + blockN + bc;

    float acc[8][8];
#pragma unroll
    for (int i = 0; i < 8; i++)
#pragma unroll
        for (int j = 0; j < 8; j++) acc[i][j] = 0.f;

    float4 a_reg = *(const float4*)(Aptr);
    float4 b_reg = *(const float4*)(Bptr);

    for (int kb = 0; kb < K; kb += 8) {
        As[ak + 0][ar] = a_reg.x;
        As[ak + 1][ar] = a_reg.y;
        As[ak + 2][ar] = a_reg.z;
        As[ak + 3][ar] = a_reg.w;
        *(float4*)&Bs[bk][bc] = b_reg;
        __syncthreads();
        if (kb + 8 < K) {
            a_reg = *(const float4*)(Aptr + kb + 8);
            b_reg = *(const float4*)(Bptr + (size_t)(kb + 8) * ldb);
        }
#pragma unroll
        for (int k = 0; k < 8; k++) {
            float4 a0 = *(const float4*)&As[k][ty * 8];
            float4 a1 = *(const float4*)&As[k][ty * 8 + 4];
            float4 b0 = *(const float4*)&Bs[k][tx * 4];
            float4 b1 = *(const float4*)&Bs[k][tx * 4 + 64];
            float av[8] = {a0.x, a0.y, a0.z, a0.w, a1.x, a1.y, a1.z, a1.w};
            float bv[8] = {b0.x, b0.y, b0.z, b0.w, b1.x, b1.y, b1.z, b1.w};
#pragma unroll
            for (int i = 0; i < 8; i++)
#pragma unroll
                for (int j = 0; j < 8; j++) acc[i][j] = fmaf(av[i], bv[j], acc[i][j]);
        }
        __syncthreads();
    }

#pragma unroll
    for (int i = 0; i < 8; i++) {
        size_t row = blockM + ty * 8 + i;
        float4 r0, r1;
        r0.x = acc[i][0]; r0.y = acc[i][1]; r0.z = acc[i][2]; r0.w = acc[i][3];
        r1.x = acc[i][4]; r1.y = acc[i][5]; r1.z = acc[i][6]; r1.w = acc[i][7];
        if (bias) {
            r0.x += bias[blockN + tx * 4 + 0]; r0.y += bias[blockN + tx * 4 + 1];
            r0.z += bias[blockN + tx * 4 + 2]; r0.w += bias[blockN + tx * 4 + 3];
            r1.x += bias[blockN + 64 + tx * 4 + 0]; r1.y += bias[blockN + 64 + tx * 4 + 1];
            r1.z += bias[blockN + 64 + tx * 4 + 2]; r1.w += bias[blockN + 64 + tx * 4 + 3];
        }
        *(float4*)(C + row * ldc + blockN + tx * 4) = r0;
        *(float4*)(C + row * ldc + blockN + 64 + tx * 4) = r1;
    }
}

// ---------------------------------------------------------------------------
// MFMA window attention. One block = (window, head, branch), 256 threads =
// 4 waves. K [256x32] and V^T [32x256] staged once as bf16 in LDS; each wave
// owns 16 query rows per q-tile (4 q-tiles). Per 32-key chunk:
//   S = Q*K^T (2 MFMAs) -> +bias, exp (C-layout) -> bf16 P via per-wave LDS
//   (C->A layout xform, wave-private, no barrier) -> O += P*V (2 MFMAs).
// Row sums accumulated per lane; quad butterfly at end; normalize at store.
// ---------------------------------------------------------------------------
__global__ __launch_bounds__(256) void attn_mfma(const float* __restrict__ qkv,
                                                 const float* __restrict__ T2,
                                                 float* __restrict__ att) {
    __shared__ unsigned short Ks[256][40];    // [key][d]  +8 pad: 20480 B
    __shared__ unsigned short Vt[32][264];    // [d][key]  +8 pad: 16896 B
    __shared__ unsigned short Pc[4][16][40];  // per-wave P chunk: 5120 B

    const int tid = threadIdx.x;
    const int wi = blockIdx.x;   // b*64 + window
    const int h = blockIdx.y;    // 0..3
    const int br = blockIdx.z;   // 0..1
    const int logW = br ? 3 : 5;
    const int Wsp = 1 << logW;
    const int Hsp = 256 >> logW;
    const int logNWx = br ? 4 : 2;
    const int b = wi >> 6;
    const int win = wi & 63;
    const int wy = win >> logNWx;
    const int wx = win & ((1 << logNWx) - 1);
    const int ccol = br * 128 + h * 32;

    // ---- stage K (bf16, [key][d]) and V^T (bf16, [d][key]) ----
#pragma unroll
    for (int it = 0; it < 8; ++it) {
        int n = it * 32 + (tid >> 3);
        int d4 = (tid & 7) * 4;
        int iy = n >> logW, ix = n & (Wsp - 1);
        size_t row = ((size_t)b * LL + (wy * Hsp + iy) * WW + wx * Wsp + ix) * 768;
        float4 kv = *(const float4*)(qkv + row + 256 + ccol + d4);
        float4 vv = *(const float4*)(qkv + row + 512 + ccol + d4);
        ushort4 kb;
        kb.x = f2bf(kv.x); kb.y = f2bf(kv.y); kb.z = f2bf(kv.z); kb.w = f2bf(kv.w);
        *(ushort4*)&Ks[n][d4] = kb;
        Vt[d4 + 0][n] = f2bf(vv.x);
        Vt[d4 + 1][n] = f2bf(vv.y);
        Vt[d4 + 2][n] = f2bf(vv.z);
        Vt[d4 + 3][n] = f2bf(vv.w);
    }
    __syncthreads();

    const int w = tid >> 6;        // wave 0..3
    const int lane = tid & 63;
    const int quad = lane >> 4;    // 0..3
    const int l15 = lane & 15;

    const f32x4 zero = {0.f, 0.f, 0.f, 0.f};

#pragma unroll 1
    for (int qt = 0; qt < 4; ++qt) {
        const int qbase = qt * 64 + w * 16;  // first query row of this wave's tile

        // Q A-frag: A[m=l15][k=quad*8+j], pre-scaled, bf16
        const int qrow = qbase + l15;
        {
        }
        const int iyq = qrow >> logW, ixq = qrow & (Wsp - 1);
        const size_t qpix = (size_t)b * LL + (wy * Hsp + iyq) * WW + wx * Wsp + ixq;
        const float* qp = qkv + qpix * 768 + ccol + quad * 8;
        float4 qa = *(const float4*)(qp);
        float4 qb = *(const float4*)(qp + 4);
        bhalf8 qfrag;
        qfrag[0] = (short)f2bf(qa.x * SCALE); qfrag[1] = (short)f2bf(qa.y * SCALE);
        qfrag[2] = (short)f2bf(qa.z * SCALE); qfrag[3] = (short)f2bf(qa.w * SCALE);
        qfrag[4] = (short)f2bf(qb.x * SCALE); qfrag[5] = (short)f2bf(qb.y * SCALE);
        qfrag[6] = (short)f2bf(qb.z * SCALE); qfrag[7] = (short)f2bf(qb.w * SCALE);

        // bias base: T2[((br*4+h)*256 + (qbase+quad*4+i))*256 + key]
        const float* Tb = T2 + (((size_t)(br * 4 + h) * 256) + (qbase + quad * 4)) * 256 + l15;

        f32x4 o0 = zero, o1 = zero;
        float rsum[4] = {0.f, 0.f, 0.f, 0.f};

#pragma unroll 2
        for (int kc = 0; kc < 8; ++kc) {
            const int kb0 = kc * 32;        // first key of tile 0
            // S = Q*K^T for two 16-key tiles
            bhalf8 kf0 = *(const bhalf8*)&Ks[kb0 + l15][quad * 8];
            bhalf8 kf1 = *(const bhalf8*)&Ks[kb0 + 16 + l15][quad * 8];
            f32x4 s0 = __builtin_amdgcn_mfma_f32_16x16x32_bf16(qfrag, kf0, zero, 0, 0, 0);
            f32x4 s1 = __builtin_amdgcn_mfma_f32_16x16x32_bf16(qfrag, kf1, zero, 0, 0, 0);

            // bias + exp, accumulate row sums, write bf16 P chunk
#pragma unroll
            for (int i = 0; i < 4; ++i) {
                float p0 = __expf(s0[i] + Tb[(size_t)i * 256 + kb0]);
                float p1 = __expf(s1[i] + Tb[(size_t)i * 256 + kb0 + 16]);
                rsum[i] += p0 + p1;
                Pc[w][quad * 4 + i][l15] = f2bf(p0);
                Pc[w][quad * 4 + i][16 + l15] = f2bf(p1);
            }
            // P A-frag (wave-private region; in-wave lgkmcnt ordering only)
            bhalf8 pf = *(const bhalf8*)&Pc[w][l15][quad * 8];
            // V B-frags: B[k=key][n=dout] from Vt[dout][key]
            bhalf8 vf0 = *(const bhalf8*)&Vt[l15][kb0 + quad * 8];
            bhalf8 vf1 = *(const bhalf8*)&Vt[16 + l15][kb0 + quad * 8];
            o0 = __builtin_amdgcn_mfma_f32_16x16x32_bf16(pf, vf0, o0, 0, 0, 0);
            o1 = __builtin_amdgcn_mfma_f32_16x16x32_bf16(pf, vf1, o1, 0, 0, 0);
        }

        // reduce row sums across the 16 lanes of each quad (keys mod 16)
#pragma unroll
        for (int i = 0; i < 4; ++i) {
            float s = rsum[i];
            s += __shfl_xor(s, 1, 64);
            s += __shfl_xor(s, 2, 64);
            s += __shfl_xor(s, 4, 64);
            s += __shfl_xor(s, 8, 64);
            rsum[i] = 1.0f / s;
        }

        // store O rows quad*4+i, cols l15 (o0) and 16+l15 (o1)
#pragma unroll
        for (int i = 0; i < 4; ++i) {
            int r = qbase + quad * 4 + i;
            int iyr = r >> logW, ixr = r & (Wsp - 1);
            size_t pix = (size_t)b * LL + (wy * Hsp + iyr) * WW + wx * Wsp + ixr;
            float* op = att + pix * 256 + ccol;
            op[l15] = o0[i] * rsum[i];
            op[16 + l15] = o1[i] * rsum[i];
        }
    }
}

// ---------------------------------------------------------------------------
// LePE: depthwise 3x3 (cross-correlation, zero pad) on V, += into att buffer.
// ---------------------------------------------------------------------------
__global__ __launch_bounds__(256) void lepe_kernel(const float* __restrict__ qkv,
                                                   const float* __restrict__ w_dw,
                                                   const float* __restrict__ b_dw,
                                                   float* __restrict__ att) {
    const int c = threadIdx.x;
    const int pix = blockIdx.x;      // b*16384 + y*128 + x
    const int bb = pix >> 14;
    const int y = (pix >> 7) & 127;
    const int x = pix & 127;
    float wloc[9];
#pragma unroll
    for (int j = 0; j < 9; j++) wloc[j] = w_dw[c * 9 + j];
    float acc = b_dw[c];
#pragma unroll
    for (int ky = 0; ky < 3; ky++) {
        int yy = y + ky - 1;
        if (yy < 0 || yy > 127) continue;
#pragma unroll
        for (int kx = 0; kx < 3; kx++) {
            int xx = x + kx - 1;
            if (xx < 0 || xx > 127) continue;
            acc = fmaf(qkv[(((size_t)bb << 14) + yy * 128 + xx) * 768 + 512 + c],
                       wloc[ky * 3 + kx], acc);
        }
    }
    att[((size_t)pix << 8) + c] += acc;
}

// ---------------------------------------------------------------------------
extern "C" void kernel_launch(void* const* d_in, const int* in_sizes, int n_in,
                              void* d_out, int out_size, void* d_ws, size_t ws_size,
                              hipStream_t stream) {
    const float* x     = (const float*)d_in[0];
    const float* w_qkv = (const float*)d_in[1];
    const float* w_proj= (const float*)d_in[2];
    const float* b_proj= (const float*)d_in[3];
    const float* w_dw  = (const float*)d_in[4];
    const float* b_dw  = (const float*)d_in[5];
    const float* pp_w  = (const float*)d_in[6];
    const float* pp_b  = (const float*)d_in[7];
    const float* ln1_g = (const float*)d_in[8];
    const float* ln1_b = (const float*)d_in[9];
    const float* l1_w  = (const float*)d_in[10];
    const float* l1_b  = (const float*)d_in[11];
    const float* ln2_g = (const float*)d_in[12];
    const float* ln2_b = (const float*)d_in[13];
    const float* l2_w  = (const float*)d_in[14];
    const float* l2_b  = (const float*)d_in[15];
    const float* ln3_g = (const float*)d_in[16];
    const float* ln3_b = (const float*)d_in[17];
    const float* l3_w  = (const float*)d_in[18];
    const float* l3_b  = (const float*)d_in[19];

    // Workspace layout (fp32 elements): tables first, then qkv. Total ~194 MiB.
    float* pos  = (float*)d_ws;                 // 7,680 floats
    float* T2   = pos + 7680;                   // 524,288 floats (2 MiB)
    float* qkv  = T2 + 524288;                  // 50,331,648 floats (192 MiB)
    float* attb = (float*)d_out;                // accumulator aliases d_out
    float* out2 = qkv;                          // gemm2 dest: qkv dead by then

    pos_kernel<<<2, 128, 0, stream>>>(pp_w, pp_b, ln1_g, ln1_b, l1_w, l1_b,
                                      ln2_g, ln2_b, l2_w, l2_b, ln3_g, ln3_b,
                                      l3_w, l3_b, pos);
    rpb_kernel<<<dim3(256, 4, 2), 256, 0, stream>>>(pos, T2);
    // qkv = x @ w_qkv   (65536 x 256) * (256 x 768)
    sgemm128<<<dim3(NROWS / 128, 768 / 128), 256, 0, stream>>>(x, w_qkv, qkv,
                                                               256, 768, 768, 256, nullptr);
    // MFMA window attention (writes every attb element)
    attn_mfma<<<dim3(256, 4, 2), 256, 0, stream>>>(qkv, T2, attb);
    // LePE += depthwise conv on V
    lepe_kernel<<<B_ * LL, 256, 0, stream>>>(qkv, w_dw, b_dw, attb);
    // out2 = attb @ w_proj + b_proj  (into dead qkv region)
    sgemm128<<<dim3(NROWS / 128, 256 / 128), 256, 0, stream>>>(attb, w_proj, out2,
                                                               256, 256, 256, 256, b_proj);
    hipMemcpyAsync(d_out, out2, (size_t)NROWS * 256 * sizeof(float),
                   hipMemcpyDeviceToDevice, stream);
}

// Round 4
// 531.052 us; speedup vs baseline: 1.8820x; 1.4345x over previous
//
#include <hip/hip_runtime.h>
#include <hip/hip_bf16.h>
#include <math.h>

// Problem constants (H=W=128 passed as inputs but fixed for this problem)
#define B_ 4
#define HH 128
#define WW 128
#define CC 256
#define LL (HH * WW)          // 16384
#define NROWS (B_ * LL)       // 65536
#define NREL 945              // (2*8-1)*(2*32-1)
#define SCALE 0.17677669529663687f  // 32^-0.5

typedef __attribute__((ext_vector_type(8))) short bhalf8;
typedef __attribute__((ext_vector_type(4))) float f32x4;

__device__ inline unsigned short f2bf(float f) {
    union { float f; unsigned u; } v; v.f = f;
    unsigned r = v.u + 0x7FFFu + ((v.u >> 16) & 1u);
    return (unsigned short)(r >> 16);
}

// exact two-term split: x = hi + r, hi = bf16(x), lo = bf16(r)
__device__ inline void split2(float x, unsigned short& h, unsigned short& l) {
    unsigned short hh = f2bf(x);
    union { unsigned u; float f; } hv; hv.u = (unsigned)hh << 16;
    h = hh;
    l = f2bf(x - hv.f);
}

// ---------------------------------------------------------------------------
// DynamicPosBias MLP: 945 rows x 2 branches, tiny. pos[br][rel][head]
// ---------------------------------------------------------------------------
__device__ inline void ln_relu8(float* v, const float* g, const float* b) {
    float m = 0.f;
#pragma unroll
    for (int j = 0; j < 8; j++) m += v[j];
    m *= 0.125f;
    float var = 0.f;
#pragma unroll
    for (int j = 0; j < 8; j++) { float d = v[j] - m; var += d * d; }
    var *= 0.125f;
    float inv = 1.0f / sqrtf(var + 1e-5f);
#pragma unroll
    for (int j = 0; j < 8; j++) {
        float xn = (v[j] - m) * inv * g[j] + b[j];
        v[j] = xn > 0.f ? xn : 0.f;
    }
}

__device__ inline void mat8x8(const float* in, float* out, const float* w, const float* bias) {
#pragma unroll
    for (int j = 0; j < 8; j++) {
        float s = bias[j];
#pragma unroll
        for (int i = 0; i < 8; i++) s = fmaf(in[i], w[i * 8 + j], s);
        out[j] = s;
    }
}

__global__ void pos_kernel(const float* __restrict__ pp_w, const float* __restrict__ pp_b,
                           const float* __restrict__ ln1_g, const float* __restrict__ ln1_b,
                           const float* __restrict__ l1_w, const float* __restrict__ l1_b,
                           const float* __restrict__ ln2_g, const float* __restrict__ ln2_b,
                           const float* __restrict__ l2_w, const float* __restrict__ l2_b,
                           const float* __restrict__ ln3_g, const float* __restrict__ ln3_b,
                           const float* __restrict__ l3_w, const float* __restrict__ l3_b,
                           float* __restrict__ pos) {
    const int br = blockIdx.x;
    const int Wsp = br ? 8 : 32;
    const int Hsp = br ? 32 : 8;
    const int W2 = 2 * Wsp - 1;
    const int nrel = (2 * Hsp - 1) * W2;  // 945 both branches
    for (int r = threadIdx.x; r < nrel; r += blockDim.x) {
        float dy = (float)(r / W2 - (Hsp - 1));
        float dx = (float)(r % W2 - (Wsp - 1));
        float p[8], t[8];
#pragma unroll
        for (int j = 0; j < 8; j++)
            p[j] = dy * pp_w[br * 16 + j] + dx * pp_w[br * 16 + 8 + j] + pp_b[br * 8 + j];
        ln_relu8(p, ln1_g + br * 8, ln1_b + br * 8);
        mat8x8(p, t, l1_w + br * 64, l1_b + br * 8);
        ln_relu8(t, ln2_g + br * 8, ln2_b + br * 8);
        mat8x8(t, p, l2_w + br * 64, l2_b + br * 8);
        ln_relu8(p, ln3_g + br * 8, ln3_b + br * 8);
#pragma unroll
        for (int j = 0; j < 4; j++) {
            float s = l3_b[br * 4 + j];
#pragma unroll
            for (int i = 0; i < 8; i++) s = fmaf(p[i], l3_w[br * 32 + i * 4 + j], s);
            pos[(br * NREL + r) * 4 + j] = s;
        }
    }
}

// T2[br][h][n(query)][m(key)] — query-major so MFMA C-layout bias reads coalesce.
__global__ void rpb_kernel(const float* __restrict__ pos, float* __restrict__ T2) {
    const int m = threadIdx.x;       // key
    const int n = blockIdx.x;        // query
    const int h = blockIdx.y;
    const int br = blockIdx.z;
    const int logW = br ? 3 : 5;
    const int Wsp = 1 << logW;
    const int Hsp = 256 >> logW;
    const int W2 = 2 * Wsp - 1;
    const int i_n = n >> logW, j_n = n & (Wsp - 1);
    const int i_m = m >> logW, j_m = m & (Wsp - 1);
    const int idx = (i_n - i_m + Hsp - 1) * W2 + (j_n - j_m + Wsp - 1);
    T2[(((size_t)(br * 4 + h) * 256) + n) * 256 + m] = pos[(br * NREL + idx) * 4 + h];
}

// Transpose + hi/lo split the weight matrix: w[K x N] fp32 -> th/tl[N x K] bf16
__global__ void convw_kernel(const float* __restrict__ w, unsigned short* __restrict__ th,
                             unsigned short* __restrict__ tl, int Kd, int Nd) {
    int idx = blockIdx.x * blockDim.x + threadIdx.x;  // n*K + k
    if (idx >= Kd * Nd) return;
    int n = idx / Kd, k = idx - n * Kd;
    unsigned short h, l;
    split2(w[(size_t)k * Nd + n], h, l);
    th[idx] = h;
    tl[idx] = l;
}

// ---------------------------------------------------------------------------
// Split-bf16 emulated SGEMM: C = A * B (+bias), fp32-accurate to ~2^-16 rel.
// A fp32 [M x K]; B pre-split/transposed bf16 Bt_hi/Bt_lo [N x K].
// 128x128 tile, BK=32, 4 waves x (4x4 tiles of 16x16), 3 MFMAs per tile:
//   Ahi*Bhi + Ahi*Blo + Alo*Bhi   (Alo*Blo ~2^-18, dropped)
// ---------------------------------------------------------------------------
__global__ __launch_bounds__(256) void gemm_split(const float* __restrict__ A,
                                                  const unsigned short* __restrict__ Bth,
                                                  const unsigned short* __restrict__ Btl,
                                                  float* __restrict__ C,
                                                  int lda, int ldc, int K,
                                                  const float* __restrict__ bias) {
    __shared__ unsigned short As_hi[128][40];  // [m][k] +8 pad (2-way only)
    __shared__ unsigned short As_lo[128][40];
    __shared__ unsigned short Bs_hi[128][40];  // [n][k]
    __shared__ unsigned short Bs_lo[128][40];

    const int tid = threadIdx.x;
    const size_t blockM = (size_t)blockIdx.x * 128;
    const int blockN = blockIdx.y * 128;

    // staging: thread t owns row t>>1, 16-element half (floats for A, ushorts for B)
    const int srow = tid >> 1;
    const int soff = (tid & 1) * 16;
    const float* Aptr = A + (blockM + srow) * lda + soff;
    const unsigned short* Bhp = Bth + (size_t)(blockN + srow) * K + soff;
    const unsigned short* Blp = Btl + (size_t)(blockN + srow) * K + soff;

    const int w = tid >> 6;
    const int lane = tid & 63;
    const int quad = lane >> 4;
    const int l15 = lane & 15;
    const int wm = (w & 1) * 64;
    const int wn = (w >> 1) * 64;

    f32x4 acc[4][4];
#pragma unroll
    for (int i = 0; i < 4; i++)
#pragma unroll
        for (int j = 0; j < 4; j++) acc[i][j] = (f32x4){0.f, 0.f, 0.f, 0.f};

    float4 a0 = *(const float4*)(Aptr + 0);
    float4 a1 = *(const float4*)(Aptr + 4);
    float4 a2 = *(const float4*)(Aptr + 8);
    float4 a3 = *(const float4*)(Aptr + 12);
    bhalf8 bh0 = *(const bhalf8*)(Bhp);
    bhalf8 bh1 = *(const bhalf8*)(Bhp + 8);
    bhalf8 bl0 = *(const bhalf8*)(Blp);
    bhalf8 bl1 = *(const bhalf8*)(Blp + 8);

    for (int kb = 0; kb < K; kb += 32) {
        // stage A (convert to hi/lo) and B
        ushort4 h4, l4;
        split2(a0.x, h4.x, l4.x); split2(a0.y, h4.y, l4.y);
        split2(a0.z, h4.z, l4.z); split2(a0.w, h4.w, l4.w);
        *(ushort4*)&As_hi[srow][soff + 0] = h4; *(ushort4*)&As_lo[srow][soff + 0] = l4;
        split2(a1.x, h4.x, l4.x); split2(a1.y, h4.y, l4.y);
        split2(a1.z, h4.z, l4.z); split2(a1.w, h4.w, l4.w);
        *(ushort4*)&As_hi[srow][soff + 4] = h4; *(ushort4*)&As_lo[srow][soff + 4] = l4;
        split2(a2.x, h4.x, l4.x); split2(a2.y, h4.y, l4.y);
        split2(a2.z, h4.z, l4.z); split2(a2.w, h4.w, l4.w);
        *(ushort4*)&As_hi[srow][soff + 8] = h4; *(ushort4*)&As_lo[srow][soff + 8] = l4;
        split2(a3.x, h4.x, l4.x); split2(a3.y, h4.y, l4.y);
        split2(a3.z, h4.z, l4.z); split2(a3.w, h4.w, l4.w);
        *(ushort4*)&As_hi[srow][soff + 12] = h4; *(ushort4*)&As_lo[srow][soff + 12] = l4;
        *(bhalf8*)&Bs_hi[srow][soff + 0] = bh0;
        *(bhalf8*)&Bs_hi[srow][soff + 8] = bh1;
        *(bhalf8*)&Bs_lo[srow][soff + 0] = bl0;
        *(bhalf8*)&Bs_lo[srow][soff + 8] = bl1;
        __syncthreads();

        if (kb + 32 < K) {
            a0 = *(const float4*)(Aptr + kb + 32 + 0);
            a1 = *(const float4*)(Aptr + kb + 32 + 4);
            a2 = *(const float4*)(Aptr + kb + 32 + 8);
            a3 = *(const float4*)(Aptr + kb + 32 + 12);
            bh0 = *(const bhalf8*)(Bhp + kb + 32);
            bh1 = *(const bhalf8*)(Bhp + kb + 32 + 8);
            bl0 = *(const bhalf8*)(Blp + kb + 32);
            bl1 = *(const bhalf8*)(Blp + kb + 32 + 8);
        }

        bhalf8 afh[4], afl[4], bfh[4], bfl[4];
#pragma unroll
        for (int i = 0; i < 4; i++) {
            afh[i] = *(const bhalf8*)&As_hi[wm + i * 16 + l15][quad * 8];
            afl[i] = *(const bhalf8*)&As_lo[wm + i * 16 + l15][quad * 8];
            bfh[i] = *(const bhalf8*)&Bs_hi[wn + i * 16 + l15][quad * 8];
            bfl[i] = *(const bhalf8*)&Bs_lo[wn + i * 16 + l15][quad * 8];
        }
#pragma unroll
        for (int i = 0; i < 4; i++)
#pragma unroll
            for (int j = 0; j < 4; j++) {
                acc[i][j] = __builtin_amdgcn_mfma_f32_16x16x32_bf16(afh[i], bfh[j], acc[i][j], 0, 0, 0);
                acc[i][j] = __builtin_amdgcn_mfma_f32_16x16x32_bf16(afh[i], bfl[j], acc[i][j], 0, 0, 0);
                acc[i][j] = __builtin_amdgcn_mfma_f32_16x16x32_bf16(afl[i], bfh[j], acc[i][j], 0, 0, 0);
            }
        __syncthreads();
    }

    // epilogue: C row = blockM+wm+i*16+quad*4+r, col = blockN+wn+j*16+l15
#pragma unroll
    for (int j = 0; j < 4; j++) {
        int col = blockN + wn + j * 16 + l15;
        float bv = bias ? bias[col] : 0.f;
#pragma unroll
        for (int i = 0; i < 4; i++) {
#pragma unroll
            for (int r = 0; r < 4; r++) {
                size_t row = blockM + wm + i * 16 + quad * 4 + r;
                C[row * ldc + col] = acc[i][j][r] + bv;
            }
        }
    }
}

// ---------------------------------------------------------------------------
// MFMA window attention (validated R2). One block = (window, head, branch).
// ---------------------------------------------------------------------------
__global__ __launch_bounds__(256) void attn_mfma(const float* __restrict__ qkv,
                                                 const float* __restrict__ T2,
                                                 float* __restrict__ att) {
    __shared__ unsigned short Ks[256][40];    // [key][d]
    __shared__ unsigned short Vt[32][264];    // [d][key]
    __shared__ unsigned short Pc[4][16][40];  // per-wave P chunk

    const int tid = threadIdx.x;
    const int wi = blockIdx.x;   // b*64 + window
    const int h = blockIdx.y;    // 0..3
    const int br = blockIdx.z;   // 0..1
    const int logW = br ? 3 : 5;
    const int Wsp = 1 << logW;
    const int Hsp = 256 >> logW;
    const int logNWx = br ? 4 : 2;
    const int b = wi >> 6;
    const int win = wi & 63;
    const int wy = win >> logNWx;
    const int wx = win & ((1 << logNWx) - 1);
    const int ccol = br * 128 + h * 32;

#pragma unroll
    for (int it = 0; it < 8; ++it) {
        int n = it * 32 + (tid >> 3);
        int d4 = (tid & 7) * 4;
        int iy = n >> logW, ix = n & (Wsp - 1);
        size_t row = ((size_t)b * LL + (wy * Hsp + iy) * WW + wx * Wsp + ix) * 768;
        float4 kv = *(const float4*)(qkv + row + 256 + ccol + d4);
        float4 vv = *(const float4*)(qkv + row + 512 + ccol + d4);
        ushort4 kb;
        kb.x = f2bf(kv.x); kb.y = f2bf(kv.y); kb.z = f2bf(kv.z); kb.w = f2bf(kv.w);
        *(ushort4*)&Ks[n][d4] = kb;
        Vt[d4 + 0][n] = f2bf(vv.x);
        Vt[d4 + 1][n] = f2bf(vv.y);
        Vt[d4 + 2][n] = f2bf(vv.z);
        Vt[d4 + 3][n] = f2bf(vv.w);
    }
    __syncthreads();

    const int w = tid >> 6;
    const int lane = tid & 63;
    const int quad = lane >> 4;
    const int l15 = lane & 15;
    const f32x4 zero = {0.f, 0.f, 0.f, 0.f};

#pragma unroll 1
    for (int qt = 0; qt < 4; ++qt) {
        const int qbase = qt * 64 + w * 16;
        const int qrow = qbase + l15;
        const int iyq = qrow >> logW, ixq = qrow & (Wsp - 1);
        const size_t qpix = (size_t)b * LL + (wy * Hsp + iyq) * WW + wx * Wsp + ixq;
        const float* qp = qkv + qpix * 768 + ccol + quad * 8;
        float4 qa = *(const float4*)(qp);
        float4 qb = *(const float4*)(qp + 4);
        bhalf8 qfrag;
        qfrag[0] = (short)f2bf(qa.x * SCALE); qfrag[1] = (short)f2bf(qa.y * SCALE);
        qfrag[2] = (short)f2bf(qa.z * SCALE); qfrag[3] = (short)f2bf(qa.w * SCALE);
        qfrag[4] = (short)f2bf(qb.x * SCALE); qfrag[5] = (short)f2bf(qb.y * SCALE);
        qfrag[6] = (short)f2bf(qb.z * SCALE); qfrag[7] = (short)f2bf(qb.w * SCALE);

        const float* Tb = T2 + (((size_t)(br * 4 + h) * 256) + (qbase + quad * 4)) * 256 + l15;

        f32x4 o0 = zero, o1 = zero;
        float rsum[4] = {0.f, 0.f, 0.f, 0.f};

#pragma unroll 2
        for (int kc = 0; kc < 8; ++kc) {
            const int kb0 = kc * 32;
            bhalf8 kf0 = *(const bhalf8*)&Ks[kb0 + l15][quad * 8];
            bhalf8 kf1 = *(const bhalf8*)&Ks[kb0 + 16 + l15][quad * 8];
            f32x4 s0 = __builtin_amdgcn_mfma_f32_16x16x32_bf16(qfrag, kf0, zero, 0, 0, 0);
            f32x4 s1 = __builtin_amdgcn_mfma_f32_16x16x32_bf16(qfrag, kf1, zero, 0, 0, 0);
#pragma unroll
            for (int i = 0; i < 4; ++i) {
                float p0 = __expf(s0[i] + Tb[(size_t)i * 256 + kb0]);
                float p1 = __expf(s1[i] + Tb[(size_t)i * 256 + kb0 + 16]);
                rsum[i] += p0 + p1;
                Pc[w][quad * 4 + i][l15] = f2bf(p0);
                Pc[w][quad * 4 + i][16 + l15] = f2bf(p1);
            }
            bhalf8 pf = *(const bhalf8*)&Pc[w][l15][quad * 8];
            bhalf8 vf0 = *(const bhalf8*)&Vt[l15][kb0 + quad * 8];
            bhalf8 vf1 = *(const bhalf8*)&Vt[16 + l15][kb0 + quad * 8];
            o0 = __builtin_amdgcn_mfma_f32_16x16x32_bf16(pf, vf0, o0, 0, 0, 0);
            o1 = __builtin_amdgcn_mfma_f32_16x16x32_bf16(pf, vf1, o1, 0, 0, 0);
        }

#pragma unroll
        for (int i = 0; i < 4; ++i) {
            float s = rsum[i];
            s += __shfl_xor(s, 1, 64);
            s += __shfl_xor(s, 2, 64);
            s += __shfl_xor(s, 4, 64);
            s += __shfl_xor(s, 8, 64);
            rsum[i] = 1.0f / s;
        }

#pragma unroll
        for (int i = 0; i < 4; ++i) {
            int r = qbase + quad * 4 + i;
            int iyr = r >> logW, ixr = r & (Wsp - 1);
            size_t pix = (size_t)b * LL + (wy * Hsp + iyr) * WW + wx * Wsp + ixr;
            float* op = att + pix * 256 + ccol;
            op[l15] = o0[i] * rsum[i];
            op[16 + l15] = o1[i] * rsum[i];
        }
    }
}

// ---------------------------------------------------------------------------
// LePE: depthwise 3x3 (cross-correlation, zero pad) on V, += into att buffer.
// ---------------------------------------------------------------------------
__global__ __launch_bounds__(256) void lepe_kernel(const float* __restrict__ qkv,
                                                   const float* __restrict__ w_dw,
                                                   const float* __restrict__ b_dw,
                                                   float* __restrict__ att) {
    const int c = threadIdx.x;
    const int pix = blockIdx.x;
    const int bb = pix >> 14;
    const int y = (pix >> 7) & 127;
    const int x = pix & 127;
    float wloc[9];
#pragma unroll
    for (int j = 0; j < 9; j++) wloc[j] = w_dw[c * 9 + j];
    float acc = b_dw[c];
#pragma unroll
    for (int ky = 0; ky < 3; ky++) {
        int yy = y + ky - 1;
        if (yy < 0 || yy > 127) continue;
#pragma unroll
        for (int kx = 0; kx < 3; kx++) {
            int xx = x + kx - 1;
            if (xx < 0 || xx > 127) continue;
            acc = fmaf(qkv[(((size_t)bb << 14) + yy * 128 + xx) * 768 + 512 + c],
                       wloc[ky * 3 + kx], acc);
        }
    }
    att[((size_t)pix << 8) + c] += acc;
}

// ---------------------------------------------------------------------------
extern "C" void kernel_launch(void* const* d_in, const int* in_sizes, int n_in,
                              void* d_out, int out_size, void* d_ws, size_t ws_size,
                              hipStream_t stream) {
    const float* x     = (const float*)d_in[0];
    const float* w_qkv = (const float*)d_in[1];
    const float* w_proj= (const float*)d_in[2];
    const float* b_proj= (const float*)d_in[3];
    const float* w_dw  = (const float*)d_in[4];
    const float* b_dw  = (const float*)d_in[5];
    const float* pp_w  = (const float*)d_in[6];
    const float* pp_b  = (const float*)d_in[7];
    const float* ln1_g = (const float*)d_in[8];
    const float* ln1_b = (const float*)d_in[9];
    const float* l1_w  = (const float*)d_in[10];
    const float* l1_b  = (const float*)d_in[11];
    const float* ln2_g = (const float*)d_in[12];
    const float* ln2_b = (const float*)d_in[13];
    const float* l2_w  = (const float*)d_in[14];
    const float* l2_b  = (const float*)d_in[15];
    const float* ln3_g = (const float*)d_in[16];
    const float* ln3_b = (const float*)d_in[17];
    const float* l3_w  = (const float*)d_in[18];
    const float* l3_b  = (const float*)d_in[19];

    // Workspace layout: tables + qkv + split/transposed weights. ~195 MiB.
    float* pos  = (float*)d_ws;                 // 7,680 floats
    float* T2   = pos + 7680;                   // 524,288 floats
    float* qkv  = T2 + 524288;                  // 50,331,648 floats (192 MiB)
    unsigned short* wqkv_h = (unsigned short*)(qkv + (size_t)NROWS * 768);
    unsigned short* wqkv_l = wqkv_h + 768 * 256;    // 196,608 each
    unsigned short* wproj_h = wqkv_l + 768 * 256;
    unsigned short* wproj_l = wproj_h + 256 * 256;  // 65,536 each
    float* attb = (float*)d_out;                // accumulator aliases d_out
    float* out2 = qkv;                          // gemm2 dest: qkv dead by then

    pos_kernel<<<2, 128, 0, stream>>>(pp_w, pp_b, ln1_g, ln1_b, l1_w, l1_b,
                                      ln2_g, ln2_b, l2_w, l2_b, ln3_g, ln3_b,
                                      l3_w, l3_b, pos);
    rpb_kernel<<<dim3(256, 4, 2), 256, 0, stream>>>(pos, T2);
    convw_kernel<<<768, 256, 0, stream>>>(w_qkv, wqkv_h, wqkv_l, 256, 768);
    convw_kernel<<<256, 256, 0, stream>>>(w_proj, wproj_h, wproj_l, 256, 256);
    // qkv = x @ w_qkv   (split-bf16 MFMA)
    gemm_split<<<dim3(NROWS / 128, 768 / 128), 256, 0, stream>>>(
        x, wqkv_h, wqkv_l, qkv, 256, 768, 256, nullptr);
    // MFMA window attention (writes every attb element)
    attn_mfma<<<dim3(256, 4, 2), 256, 0, stream>>>(qkv, T2, attb);
    // LePE += depthwise conv on V
    lepe_kernel<<<B_ * LL, 256, 0, stream>>>(qkv, w_dw, b_dw, attb);
    // out2 = attb @ w_proj + b_proj  (split-bf16 MFMA, into dead qkv region)
    gemm_split<<<dim3(NROWS / 128, 256 / 128), 256, 0, stream>>>(
        attb, wproj_h, wproj_l, out2, 256, 256, 256, b_proj);
    hipMemcpyAsync(d_out, out2, (size_t)NROWS * 256 * sizeof(float),
                   hipMemcpyDeviceToDevice, stream);
}

// Round 5
// 480.692 us; speedup vs baseline: 2.0792x; 1.1048x over previous
//
#include <hip/hip_runtime.h>
#include <hip/hip_bf16.h>
#include <math.h>

// Problem constants (H=W=128 passed as inputs but fixed for this problem)
#define B_ 4
#define HH 128
#define WW 128
#define CC 256
#define LL (HH * WW)          // 16384
#define NROWS (B_ * LL)       // 65536
#define NREL 945              // (2*8-1)*(2*32-1)
#define SCALE 0.17677669529663687f  // 32^-0.5

typedef __attribute__((ext_vector_type(8))) short bhalf8;
typedef __attribute__((ext_vector_type(4))) float f32x4;

__device__ inline unsigned short f2bf(float f) {
    union { float f; unsigned u; } v; v.f = f;
    unsigned r = v.u + 0x7FFFu + ((v.u >> 16) & 1u);
    return (unsigned short)(r >> 16);
}

// exact two-term split: x = hi + r, hi = bf16(x), lo = bf16(r)
__device__ inline void split2(float x, unsigned short& h, unsigned short& l) {
    unsigned short hh = f2bf(x);
    union { unsigned u; float f; } hv; hv.u = (unsigned)hh << 16;
    h = hh;
    l = f2bf(x - hv.f);
}

// ---------------------------------------------------------------------------
// DynamicPosBias MLP: 945 rows x 2 branches, tiny. pos[br][rel][head]
// ---------------------------------------------------------------------------
__device__ inline void ln_relu8(float* v, const float* g, const float* b) {
    float m = 0.f;
#pragma unroll
    for (int j = 0; j < 8; j++) m += v[j];
    m *= 0.125f;
    float var = 0.f;
#pragma unroll
    for (int j = 0; j < 8; j++) { float d = v[j] - m; var += d * d; }
    var *= 0.125f;
    float inv = 1.0f / sqrtf(var + 1e-5f);
#pragma unroll
    for (int j = 0; j < 8; j++) {
        float xn = (v[j] - m) * inv * g[j] + b[j];
        v[j] = xn > 0.f ? xn : 0.f;
    }
}

__device__ inline void mat8x8(const float* in, float* out, const float* w, const float* bias) {
#pragma unroll
    for (int j = 0; j < 8; j++) {
        float s = bias[j];
#pragma unroll
        for (int i = 0; i < 8; i++) s = fmaf(in[i], w[i * 8 + j], s);
        out[j] = s;
    }
}

__global__ void pos_kernel(const float* __restrict__ pp_w, const float* __restrict__ pp_b,
                           const float* __restrict__ ln1_g, const float* __restrict__ ln1_b,
                           const float* __restrict__ l1_w, const float* __restrict__ l1_b,
                           const float* __restrict__ ln2_g, const float* __restrict__ ln2_b,
                           const float* __restrict__ l2_w, const float* __restrict__ l2_b,
                           const float* __restrict__ ln3_g, const float* __restrict__ ln3_b,
                           const float* __restrict__ l3_w, const float* __restrict__ l3_b,
                           float* __restrict__ pos) {
    const int br = blockIdx.x;
    const int Wsp = br ? 8 : 32;
    const int Hsp = br ? 32 : 8;
    const int W2 = 2 * Wsp - 1;
    const int nrel = (2 * Hsp - 1) * W2;  // 945 both branches
    for (int r = threadIdx.x; r < nrel; r += blockDim.x) {
        float dy = (float)(r / W2 - (Hsp - 1));
        float dx = (float)(r % W2 - (Wsp - 1));
        float p[8], t[8];
#pragma unroll
        for (int j = 0; j < 8; j++)
            p[j] = dy * pp_w[br * 16 + j] + dx * pp_w[br * 16 + 8 + j] + pp_b[br * 8 + j];
        ln_relu8(p, ln1_g + br * 8, ln1_b + br * 8);
        mat8x8(p, t, l1_w + br * 64, l1_b + br * 8);
        ln_relu8(t, ln2_g + br * 8, ln2_b + br * 8);
        mat8x8(t, p, l2_w + br * 64, l2_b + br * 8);
        ln_relu8(p, ln3_g + br * 8, ln3_b + br * 8);
#pragma unroll
        for (int j = 0; j < 4; j++) {
            float s = l3_b[br * 4 + j];
#pragma unroll
            for (int i = 0; i < 8; i++) s = fmaf(p[i], l3_w[br * 32 + i * 4 + j], s);
            pos[(br * NREL + r) * 4 + j] = s;
        }
    }
}

// T2[br][h][n(query)][m(key)] — query-major so MFMA C-layout bias reads coalesce.
__global__ void rpb_kernel(const float* __restrict__ pos, float* __restrict__ T2) {
    const int m = threadIdx.x;       // key
    const int n = blockIdx.x;        // query
    const int h = blockIdx.y;
    const int br = blockIdx.z;
    const int logW = br ? 3 : 5;
    const int Wsp = 1 << logW;
    const int Hsp = 256 >> logW;
    const int W2 = 2 * Wsp - 1;
    const int i_n = n >> logW, j_n = n & (Wsp - 1);
    const int i_m = m >> logW, j_m = m & (Wsp - 1);
    const int idx = (i_n - i_m + Hsp - 1) * W2 + (j_n - j_m + Wsp - 1);
    T2[(((size_t)(br * 4 + h) * 256) + n) * 256 + m] = pos[(br * NREL + idx) * 4 + h];
}

// Transpose + hi/lo split the weight matrix: w[K x N] fp32 -> th/tl[N x K] bf16
__global__ void convw_kernel(const float* __restrict__ w, unsigned short* __restrict__ th,
                             unsigned short* __restrict__ tl, int Kd, int Nd) {
    int idx = blockIdx.x * blockDim.x + threadIdx.x;  // n*K + k
    if (idx >= Kd * Nd) return;
    int n = idx / Kd, k = idx - n * Kd;
    unsigned short h, l;
    split2(w[(size_t)k * Nd + n], h, l);
    th[idx] = h;
    tl[idx] = l;
}

// ---------------------------------------------------------------------------
// Split-bf16 emulated SGEMM: C = A * B (+bias), fp32-accurate to ~2^-16 rel.
// A fp32 [M x K]; B pre-split/transposed bf16 Bt_hi/Bt_lo [N x K].
// 128x128 tile, BK=32, 4 waves x (4x4 tiles of 16x16), 3 MFMAs per tile:
//   Ahi*Bhi + Ahi*Blo + Alo*Bhi   (Alo*Blo ~2^-18, dropped)
// ---------------------------------------------------------------------------
__global__ __launch_bounds__(256) void gemm_split(const float* __restrict__ A,
                                                  const unsigned short* __restrict__ Bth,
                                                  const unsigned short* __restrict__ Btl,
                                                  float* __restrict__ C,
                                                  int lda, int ldc, int K,
                                                  const float* __restrict__ bias) {
    __shared__ unsigned short As_hi[128][40];  // [m][k] +8 pad (2-way only)
    __shared__ unsigned short As_lo[128][40];
    __shared__ unsigned short Bs_hi[128][40];  // [n][k]
    __shared__ unsigned short Bs_lo[128][40];

    const int tid = threadIdx.x;
    const size_t blockM = (size_t)blockIdx.x * 128;
    const int blockN = blockIdx.y * 128;

    // staging: thread t owns row t>>1, 16-element half (floats for A, ushorts for B)
    const int srow = tid >> 1;
    const int soff = (tid & 1) * 16;
    const float* Aptr = A + (blockM + srow) * lda + soff;
    const unsigned short* Bhp = Bth + (size_t)(blockN + srow) * K + soff;
    const unsigned short* Blp = Btl + (size_t)(blockN + srow) * K + soff;

    const int w = tid >> 6;
    const int lane = tid & 63;
    const int quad = lane >> 4;
    const int l15 = lane & 15;
    const int wm = (w & 1) * 64;
    const int wn = (w >> 1) * 64;

    f32x4 acc[4][4];
#pragma unroll
    for (int i = 0; i < 4; i++)
#pragma unroll
        for (int j = 0; j < 4; j++) acc[i][j] = (f32x4){0.f, 0.f, 0.f, 0.f};

    float4 a0 = *(const float4*)(Aptr + 0);
    float4 a1 = *(const float4*)(Aptr + 4);
    float4 a2 = *(const float4*)(Aptr + 8);
    float4 a3 = *(const float4*)(Aptr + 12);
    bhalf8 bh0 = *(const bhalf8*)(Bhp);
    bhalf8 bh1 = *(const bhalf8*)(Bhp + 8);
    bhalf8 bl0 = *(const bhalf8*)(Blp);
    bhalf8 bl1 = *(const bhalf8*)(Blp + 8);

    for (int kb = 0; kb < K; kb += 32) {
        // stage A (convert to hi/lo) and B
        ushort4 h4, l4;
        split2(a0.x, h4.x, l4.x); split2(a0.y, h4.y, l4.y);
        split2(a0.z, h4.z, l4.z); split2(a0.w, h4.w, l4.w);
        *(ushort4*)&As_hi[srow][soff + 0] = h4; *(ushort4*)&As_lo[srow][soff + 0] = l4;
        split2(a1.x, h4.x, l4.x); split2(a1.y, h4.y, l4.y);
        split2(a1.z, h4.z, l4.z); split2(a1.w, h4.w, l4.w);
        *(ushort4*)&As_hi[srow][soff + 4] = h4; *(ushort4*)&As_lo[srow][soff + 4] = l4;
        split2(a2.x, h4.x, l4.x); split2(a2.y, h4.y, l4.y);
        split2(a2.z, h4.z, l4.z); split2(a2.w, h4.w, l4.w);
        *(ushort4*)&As_hi[srow][soff + 8] = h4; *(ushort4*)&As_lo[srow][soff + 8] = l4;
        split2(a3.x, h4.x, l4.x); split2(a3.y, h4.y, l4.y);
        split2(a3.z, h4.z, l4.z); split2(a3.w, h4.w, l4.w);
        *(ushort4*)&As_hi[srow][soff + 12] = h4; *(ushort4*)&As_lo[srow][soff + 12] = l4;
        *(bhalf8*)&Bs_hi[srow][soff + 0] = bh0;
        *(bhalf8*)&Bs_hi[srow][soff + 8] = bh1;
        *(bhalf8*)&Bs_lo[srow][soff + 0] = bl0;
        *(bhalf8*)&Bs_lo[srow][soff + 8] = bl1;
        __syncthreads();

        if (kb + 32 < K) {
            a0 = *(const float4*)(Aptr + kb + 32 + 0);
            a1 = *(const float4*)(Aptr + kb + 32 + 4);
            a2 = *(const float4*)(Aptr + kb + 32 + 8);
            a3 = *(const float4*)(Aptr + kb + 32 + 12);
            bh0 = *(const bhalf8*)(Bhp + kb + 32);
            bh1 = *(const bhalf8*)(Bhp + kb + 32 + 8);
            bl0 = *(const bhalf8*)(Blp + kb + 32);
            bl1 = *(const bhalf8*)(Blp + kb + 32 + 8);
        }

        bhalf8 afh[4], afl[4], bfh[4], bfl[4];
#pragma unroll
        for (int i = 0; i < 4; i++) {
            afh[i] = *(const bhalf8*)&As_hi[wm + i * 16 + l15][quad * 8];
            afl[i] = *(const bhalf8*)&As_lo[wm + i * 16 + l15][quad * 8];
            bfh[i] = *(const bhalf8*)&Bs_hi[wn + i * 16 + l15][quad * 8];
            bfl[i] = *(const bhalf8*)&Bs_lo[wn + i * 16 + l15][quad * 8];
        }
#pragma unroll
        for (int i = 0; i < 4; i++)
#pragma unroll
            for (int j = 0; j < 4; j++) {
                acc[i][j] = __builtin_amdgcn_mfma_f32_16x16x32_bf16(afh[i], bfh[j], acc[i][j], 0, 0, 0);
                acc[i][j] = __builtin_amdgcn_mfma_f32_16x16x32_bf16(afh[i], bfl[j], acc[i][j], 0, 0, 0);
                acc[i][j] = __builtin_amdgcn_mfma_f32_16x16x32_bf16(afl[i], bfh[j], acc[i][j], 0, 0, 0);
            }
        __syncthreads();
    }

    // epilogue: C row = blockM+wm+i*16+quad*4+r, col = blockN+wn+j*16+l15
#pragma unroll
    for (int j = 0; j < 4; j++) {
        int col = blockN + wn + j * 16 + l15;
        float bv = bias ? bias[col] : 0.f;
#pragma unroll
        for (int i = 0; i < 4; i++) {
#pragma unroll
            for (int r = 0; r < 4; r++) {
                size_t row = blockM + wm + i * 16 + quad * 4 + r;
                C[row * ldc + col] = acc[i][j][r] + bv;
            }
        }
    }
}

// ---------------------------------------------------------------------------
// MFMA window attention (validated R2). One block = (window, head, branch).
// ---------------------------------------------------------------------------
__global__ __launch_bounds__(256) void attn_mfma(const float* __restrict__ qkv,
                                                 const float* __restrict__ T2,
                                                 float* __restrict__ att) {
    __shared__ unsigned short Ks[256][40];    // [key][d]
    __shared__ unsigned short Vt[32][264];    // [d][key]
    __shared__ unsigned short Pc[4][16][40];  // per-wave P chunk

    const int tid = threadIdx.x;
    const int wi = blockIdx.x;   // b*64 + window
    const int h = blockIdx.y;    // 0..3
    const int br = blockIdx.z;   // 0..1
    const int logW = br ? 3 : 5;
    const int Wsp = 1 << logW;
    const int Hsp = 256 >> logW;
    const int logNWx = br ? 4 : 2;
    const int b = wi >> 6;
    const int win = wi & 63;
    const int wy = win >> logNWx;
    const int wx = win & ((1 << logNWx) - 1);
    const int ccol = br * 128 + h * 32;

#pragma unroll
    for (int it = 0; it < 8; ++it) {
        int n = it * 32 + (tid >> 3);
        int d4 = (tid & 7) * 4;
        int iy = n >> logW, ix = n & (Wsp - 1);
        size_t row = ((size_t)b * LL + (wy * Hsp + iy) * WW + wx * Wsp + ix) * 768;
        float4 kv = *(const float4*)(qkv + row + 256 + ccol + d4);
        float4 vv = *(const float4*)(qkv + row + 512 + ccol + d4);
        ushort4 kb;
        kb.x = f2bf(kv.x); kb.y = f2bf(kv.y); kb.z = f2bf(kv.z); kb.w = f2bf(kv.w);
        *(ushort4*)&Ks[n][d4] = kb;
        Vt[d4 + 0][n] = f2bf(vv.x);
        Vt[d4 + 1][n] = f2bf(vv.y);
        Vt[d4 + 2][n] = f2bf(vv.z);
        Vt[d4 + 3][n] = f2bf(vv.w);
    }
    __syncthreads();

    const int w = tid >> 6;
    const int lane = tid & 63;
    const int quad = lane >> 4;
    const int l15 = lane & 15;
    const f32x4 zero = {0.f, 0.f, 0.f, 0.f};

#pragma unroll 1
    for (int qt = 0; qt < 4; ++qt) {
        const int qbase = qt * 64 + w * 16;
        const int qrow = qbase + l15;
        const int iyq = qrow >> logW, ixq = qrow & (Wsp - 1);
        const size_t qpix = (size_t)b * LL + (wy * Hsp + iyq) * WW + wx * Wsp + ixq;
        const float* qp = qkv + qpix * 768 + ccol + quad * 8;
        float4 qa = *(const float4*)(qp);
        float4 qb = *(const float4*)(qp + 4);
        bhalf8 qfrag;
        qfrag[0] = (short)f2bf(qa.x * SCALE); qfrag[1] = (short)f2bf(qa.y * SCALE);
        qfrag[2] = (short)f2bf(qa.z * SCALE); qfrag[3] = (short)f2bf(qa.w * SCALE);
        qfrag[4] = (short)f2bf(qb.x * SCALE); qfrag[5] = (short)f2bf(qb.y * SCALE);
        qfrag[6] = (short)f2bf(qb.z * SCALE); qfrag[7] = (short)f2bf(qb.w * SCALE);

        const float* Tb = T2 + (((size_t)(br * 4 + h) * 256) + (qbase + quad * 4)) * 256 + l15;

        f32x4 o0 = zero, o1 = zero;
        float rsum[4] = {0.f, 0.f, 0.f, 0.f};

#pragma unroll 2
        for (int kc = 0; kc < 8; ++kc) {
            const int kb0 = kc * 32;
            bhalf8 kf0 = *(const bhalf8*)&Ks[kb0 + l15][quad * 8];
            bhalf8 kf1 = *(const bhalf8*)&Ks[kb0 + 16 + l15][quad * 8];
            f32x4 s0 = __builtin_amdgcn_mfma_f32_16x16x32_bf16(qfrag, kf0, zero, 0, 0, 0);
            f32x4 s1 = __builtin_amdgcn_mfma_f32_16x16x32_bf16(qfrag, kf1, zero, 0, 0, 0);
#pragma unroll
            for (int i = 0; i < 4; ++i) {
                float p0 = __expf(s0[i] + Tb[(size_t)i * 256 + kb0]);
                float p1 = __expf(s1[i] + Tb[(size_t)i * 256 + kb0 + 16]);
                rsum[i] += p0 + p1;
                Pc[w][quad * 4 + i][l15] = f2bf(p0);
                Pc[w][quad * 4 + i][16 + l15] = f2bf(p1);
            }
            bhalf8 pf = *(const bhalf8*)&Pc[w][l15][quad * 8];
            bhalf8 vf0 = *(const bhalf8*)&Vt[l15][kb0 + quad * 8];
            bhalf8 vf1 = *(const bhalf8*)&Vt[16 + l15][kb0 + quad * 8];
            o0 = __builtin_amdgcn_mfma_f32_16x16x32_bf16(pf, vf0, o0, 0, 0, 0);
            o1 = __builtin_amdgcn_mfma_f32_16x16x32_bf16(pf, vf1, o1, 0, 0, 0);
        }

#pragma unroll
        for (int i = 0; i < 4; ++i) {
            float s = rsum[i];
            s += __shfl_xor(s, 1, 64);
            s += __shfl_xor(s, 2, 64);
            s += __shfl_xor(s, 4, 64);
            s += __shfl_xor(s, 8, 64);
            rsum[i] = 1.0f / s;
        }

#pragma unroll
        for (int i = 0; i < 4; ++i) {
            int r = qbase + quad * 4 + i;
            int iyr = r >> logW, ixr = r & (Wsp - 1);
            size_t pix = (size_t)b * LL + (wy * Hsp + iyr) * WW + wx * Wsp + ixr;
            float* op = att + pix * 256 + ccol;
            op[l15] = o0[i] * rsum[i];
            op[16 + l15] = o1[i] * rsum[i];
        }
    }
}

// ---------------------------------------------------------------------------
// LePE: depthwise 3x3 (cross-correlation, zero pad) on V, += into att buffer.
// Vectorized float4-over-channels: thread = (pixel, channel-quad).
// 4 pixels per block; weights for a channel-quad are 36 contiguous floats.
// ---------------------------------------------------------------------------
__global__ __launch_bounds__(256) void lepe_kernel(const float* __restrict__ qkv,
                                                   const float* __restrict__ w_dw,
                                                   const float* __restrict__ b_dw,
                                                   float* __restrict__ att) {
    const int tid = threadIdx.x;
    const int c4 = (tid & 63) * 4;               // channel quad base
    const int pix = blockIdx.x * 4 + (tid >> 6); // 4 pixels per block
    const int bb = pix >> 14;
    const int y = (pix >> 7) & 127;
    const int x = pix & 127;

    // weights for channels c4..c4+3: 36 contiguous floats at w_dw + c4*9
    float wreg[36];
    const float* wp = w_dw + c4 * 9;
#pragma unroll
    for (int q = 0; q < 9; q++) {
        float4 t = *(const float4*)(wp + q * 4);
        wreg[q * 4 + 0] = t.x; wreg[q * 4 + 1] = t.y;
        wreg[q * 4 + 2] = t.z; wreg[q * 4 + 3] = t.w;
    }
    // wreg[i*9 + j] = weight for channel c4+i, tap j

    float4 bv = *(const float4*)(b_dw + c4);
    float4 av = *(const float4*)(att + ((size_t)pix << 8) + c4);
    float4 acc;
    acc.x = av.x + bv.x; acc.y = av.y + bv.y;
    acc.z = av.z + bv.z; acc.w = av.w + bv.w;

#pragma unroll
    for (int ky = 0; ky < 3; ky++) {
        int yy = y + ky - 1;
        if (yy < 0 || yy > 127) continue;
#pragma unroll
        for (int kx = 0; kx < 3; kx++) {
            int xx = x + kx - 1;
            if (xx < 0 || xx > 127) continue;
            int j = ky * 3 + kx;
            float4 v = *(const float4*)(qkv + (((size_t)bb << 14) + yy * 128 + xx) * 768 + 512 + c4);
            acc.x = fmaf(v.x, wreg[0 * 9 + j], acc.x);
            acc.y = fmaf(v.y, wreg[1 * 9 + j], acc.y);
            acc.z = fmaf(v.z, wreg[2 * 9 + j], acc.z);
            acc.w = fmaf(v.w, wreg[3 * 9 + j], acc.w);
        }
    }
    *(float4*)(att + ((size_t)pix << 8) + c4) = acc;
}

// ---------------------------------------------------------------------------
extern "C" void kernel_launch(void* const* d_in, const int* in_sizes, int n_in,
                              void* d_out, int out_size, void* d_ws, size_t ws_size,
                              hipStream_t stream) {
    const float* x     = (const float*)d_in[0];
    const float* w_qkv = (const float*)d_in[1];
    const float* w_proj= (const float*)d_in[2];
    const float* b_proj= (const float*)d_in[3];
    const float* w_dw  = (const float*)d_in[4];
    const float* b_dw  = (const float*)d_in[5];
    const float* pp_w  = (const float*)d_in[6];
    const float* pp_b  = (const float*)d_in[7];
    const float* ln1_g = (const float*)d_in[8];
    const float* ln1_b = (const float*)d_in[9];
    const float* l1_w  = (const float*)d_in[10];
    const float* l1_b  = (const float*)d_in[11];
    const float* ln2_g = (const float*)d_in[12];
    const float* ln2_b = (const float*)d_in[13];
    const float* l2_w  = (const float*)d_in[14];
    const float* l2_b  = (const float*)d_in[15];
    const float* ln3_g = (const float*)d_in[16];
    const float* ln3_b = (const float*)d_in[17];
    const float* l3_w  = (const float*)d_in[18];
    const float* l3_b  = (const float*)d_in[19];

    // Workspace layout: tables + qkv + split/transposed weights. ~195 MiB.
    float* pos  = (float*)d_ws;                 // 7,680 floats
    float* T2   = pos + 7680;                   // 524,288 floats
    float* qkv  = T2 + 524288;                  // 50,331,648 floats (192 MiB)
    unsigned short* wqkv_h = (unsigned short*)(qkv + (size_t)NROWS * 768);
    unsigned short* wqkv_l = wqkv_h + 768 * 256;    // 196,608 each
    unsigned short* wproj_h = wqkv_l + 768 * 256;
    unsigned short* wproj_l = wproj_h + 256 * 256;  // 65,536 each
    float* attb = (float*)d_out;                // accumulator aliases d_out
    float* out2 = qkv;                          // gemm2 dest: qkv dead by then

    pos_kernel<<<2, 128, 0, stream>>>(pp_w, pp_b, ln1_g, ln1_b, l1_w, l1_b,
                                      ln2_g, ln2_b, l2_w, l2_b, ln3_g, ln3_b,
                                      l3_w, l3_b, pos);
    rpb_kernel<<<dim3(256, 4, 2), 256, 0, stream>>>(pos, T2);
    convw_kernel<<<768, 256, 0, stream>>>(w_qkv, wqkv_h, wqkv_l, 256, 768);
    convw_kernel<<<256, 256, 0, stream>>>(w_proj, wproj_h, wproj_l, 256, 256);
    // qkv = x @ w_qkv   (split-bf16 MFMA)
    gemm_split<<<dim3(NROWS / 128, 768 / 128), 256, 0, stream>>>(
        x, wqkv_h, wqkv_l, qkv, 256, 768, 256, nullptr);
    // MFMA window attention (writes every attb element)
    attn_mfma<<<dim3(256, 4, 2), 256, 0, stream>>>(qkv, T2, attb);
    // LePE += depthwise conv on V (float4 over channels, 4 pixels/block)
    lepe_kernel<<<(B_ * LL) / 4, 256, 0, stream>>>(qkv, w_dw, b_dw, attb);
    // out2 = attb @ w_proj + b_proj  (split-bf16 MFMA, into dead qkv region)
    gemm_split<<<dim3(NROWS / 128, 256 / 128), 256, 0, stream>>>(
        attb, wproj_h, wproj_l, out2, 256, 256, 256, b_proj);
    hipMemcpyAsync(d_out, out2, (size_t)NROWS * 256 * sizeof(float),
                   hipMemcpyDeviceToDevice, stream);
}

// Round 6
// 434.818 us; speedup vs baseline: 2.2986x; 1.1055x over previous
//
#include <hip/hip_runtime.h>
#include <hip/hip_bf16.h>
#include <math.h>

// Problem constants (H=W=128 passed as inputs but fixed for this problem)
#define B_ 4
#define HH 128
#define WW 128
#define CC 256
#define LL (HH * WW)          // 16384
#define NROWS (B_ * LL)       // 65536
#define NREL 945              // (2*8-1)*(2*32-1)
#define SCALE 0.17677669529663687f  // 32^-0.5

typedef __attribute__((ext_vector_type(8))) short bhalf8;
typedef __attribute__((ext_vector_type(4))) float f32x4;

__device__ __forceinline__ unsigned short f2bf(float f) {
    union { float f; unsigned u; } v; v.f = f;
    unsigned r = v.u + 0x7FFFu + ((v.u >> 16) & 1u);
    return (unsigned short)(r >> 16);
}
__device__ __forceinline__ float b2f(unsigned short u) {
    union { unsigned u; float f; } v; v.u = (unsigned)u << 16; return v.f;
}
// exact two-term split: x = hi + r, hi = bf16(x), lo = bf16(r)
__device__ __forceinline__ void split2(float x, unsigned short& h, unsigned short& l) {
    unsigned short hh = f2bf(x);
    h = hh;
    l = f2bf(x - b2f(hh));
}
// async global->LDS, 16 B per lane (dest = wave-uniform base + lane*16)
__device__ __forceinline__ void gl_lds16(const unsigned short* g, unsigned short* l) {
    __builtin_amdgcn_global_load_lds((const __attribute__((address_space(1))) void*)g,
                                     (__attribute__((address_space(3))) void*)l, 16, 0, 0);
}

// ---------------------------------------------------------------------------
// DynamicPosBias MLP (tiny) + bias-table expansion (unchanged, validated)
// ---------------------------------------------------------------------------
__device__ inline void ln_relu8(float* v, const float* g, const float* b) {
    float m = 0.f;
#pragma unroll
    for (int j = 0; j < 8; j++) m += v[j];
    m *= 0.125f;
    float var = 0.f;
#pragma unroll
    for (int j = 0; j < 8; j++) { float d = v[j] - m; var += d * d; }
    var *= 0.125f;
    float inv = 1.0f / sqrtf(var + 1e-5f);
#pragma unroll
    for (int j = 0; j < 8; j++) {
        float xn = (v[j] - m) * inv * g[j] + b[j];
        v[j] = xn > 0.f ? xn : 0.f;
    }
}

__device__ inline void mat8x8(const float* in, float* out, const float* w, const float* bias) {
#pragma unroll
    for (int j = 0; j < 8; j++) {
        float s = bias[j];
#pragma unroll
        for (int i = 0; i < 8; i++) s = fmaf(in[i], w[i * 8 + j], s);
        out[j] = s;
    }
}

__global__ void pos_kernel(const float* __restrict__ pp_w, const float* __restrict__ pp_b,
                           const float* __restrict__ ln1_g, const float* __restrict__ ln1_b,
                           const float* __restrict__ l1_w, const float* __restrict__ l1_b,
                           const float* __restrict__ ln2_g, const float* __restrict__ ln2_b,
                           const float* __restrict__ l2_w, const float* __restrict__ l2_b,
                           const float* __restrict__ ln3_g, const float* __restrict__ ln3_b,
                           const float* __restrict__ l3_w, const float* __restrict__ l3_b,
                           float* __restrict__ pos) {
    const int br = blockIdx.x;
    const int Wsp = br ? 8 : 32;
    const int Hsp = br ? 32 : 8;
    const int W2 = 2 * Wsp - 1;
    const int nrel = (2 * Hsp - 1) * W2;  // 945 both branches
    for (int r = threadIdx.x; r < nrel; r += blockDim.x) {
        float dy = (float)(r / W2 - (Hsp - 1));
        float dx = (float)(r % W2 - (Wsp - 1));
        float p[8], t[8];
#pragma unroll
        for (int j = 0; j < 8; j++)
            p[j] = dy * pp_w[br * 16 + j] + dx * pp_w[br * 16 + 8 + j] + pp_b[br * 8 + j];
        ln_relu8(p, ln1_g + br * 8, ln1_b + br * 8);
        mat8x8(p, t, l1_w + br * 64, l1_b + br * 8);
        ln_relu8(t, ln2_g + br * 8, ln2_b + br * 8);
        mat8x8(t, p, l2_w + br * 64, l2_b + br * 8);
        ln_relu8(p, ln3_g + br * 8, ln3_b + br * 8);
#pragma unroll
        for (int j = 0; j < 4; j++) {
            float s = l3_b[br * 4 + j];
#pragma unroll
            for (int i = 0; i < 8; i++) s = fmaf(p[i], l3_w[br * 32 + i * 4 + j], s);
            pos[(br * NREL + r) * 4 + j] = s;
        }
    }
}

// T2[br][h][n(query)][m(key)]
__global__ void rpb_kernel(const float* __restrict__ pos, float* __restrict__ T2) {
    const int m = threadIdx.x;       // key
    const int n = blockIdx.x;        // query
    const int h = blockIdx.y;
    const int br = blockIdx.z;
    const int logW = br ? 3 : 5;
    const int Wsp = 1 << logW;
    const int Hsp = 256 >> logW;
    const int W2 = 2 * Wsp - 1;
    const int i_n = n >> logW, j_n = n & (Wsp - 1);
    const int i_m = m >> logW, j_m = m & (Wsp - 1);
    const int idx = (i_n - i_m + Hsp - 1) * W2 + (j_n - j_m + Wsp - 1);
    T2[(((size_t)(br * 4 + h) * 256) + n) * 256 + m] = pos[(br * NREL + idx) * 4 + h];
}

// Transpose + hi/lo split weights: w[K x N] fp32 -> th/tl[N x K] bf16
__global__ void convw_kernel(const float* __restrict__ w, unsigned short* __restrict__ th,
                             unsigned short* __restrict__ tl, int Kd, int Nd) {
    int idx = blockIdx.x * blockDim.x + threadIdx.x;  // n*K + k
    if (idx >= Kd * Nd) return;
    int n = idx / Kd, k = idx - n * Kd;
    unsigned short h, l;
    split2(w[(size_t)k * Nd + n], h, l);
    th[idx] = h;
    tl[idx] = l;
}

// x fp32 [M][256] -> x_hi, x_lo bf16 (row-major)
__global__ __launch_bounds__(256) void convx_kernel(const float* __restrict__ x,
                                                    unsigned short* __restrict__ xh,
                                                    unsigned short* __restrict__ xl) {
    size_t i = ((size_t)blockIdx.x * 256 + threadIdx.x) * 4;
    float4 v = *(const float4*)(x + i);
    ushort4 h, l;
    split2(v.x, h.x, l.x); split2(v.y, h.y, l.y);
    split2(v.z, h.z, l.z); split2(v.w, h.w, l.w);
    *(ushort4*)(xh + i) = h;
    *(ushort4*)(xl + i) = l;
}

// ---------------------------------------------------------------------------
// gemm1: C_bf16[M][ldc] = (Ah+Al) @ (Bh+Bl)^T, 3-term split-bf16.
// All operands bf16; LDS staged via global_load_lds (m97 2-barrier K-loop).
// 128x128 tile, BK=32, 4 waves x 4x4 16x16 tiles. N-block fastest for A reuse.
// ---------------------------------------------------------------------------
__global__ __launch_bounds__(256) void gemm_bf3(const unsigned short* __restrict__ Ah,
                                                const unsigned short* __restrict__ Al,
                                                const unsigned short* __restrict__ Bh,
                                                const unsigned short* __restrict__ Bl,
                                                unsigned short* __restrict__ C,
                                                int ldc, int nblk) {
    const int K = 256;
    __shared__ unsigned short sAh[4096];  // [128][32]
    __shared__ unsigned short sAl[4096];
    __shared__ unsigned short sBh[4096];
    __shared__ unsigned short sBl[4096];

    const int tid = threadIdx.x;
    const int nb = blockIdx.x % nblk;          // N fastest: A-tile L2/L3 reuse
    const int mb = blockIdx.x / nblk;
    const size_t blockM = (size_t)mb * 128;
    const int blockN = nb * 128;

    const int srow = tid >> 2;                 // staging row 0..63
    const int schunk = (tid & 3) * 8;          // k-chunk
    const unsigned short* pAh = Ah + (blockM + srow) * K + schunk;
    const unsigned short* pAl = Al + (blockM + srow) * K + schunk;
    const unsigned short* pBh = Bh + (size_t)(blockN + srow) * K + schunk;
    const unsigned short* pBl = Bl + (size_t)(blockN + srow) * K + schunk;
    const size_t rstep = (size_t)64 * K;

    const int w = tid >> 6;
    const int lane = tid & 63;
    const int quad = lane >> 4;
    const int l15 = lane & 15;
    const int wm = (w & 1) * 64;
    const int wn = (w >> 1) * 64;

    f32x4 acc[4][4];
#pragma unroll
    for (int i = 0; i < 4; i++)
#pragma unroll
        for (int j = 0; j < 4; j++) acc[i][j] = (f32x4){0.f, 0.f, 0.f, 0.f};

    for (int kb = 0; kb < K; kb += 32) {
        gl_lds16(pAh + kb, sAh + tid * 8);
        gl_lds16(pAh + kb + rstep, sAh + 2048 + tid * 8);
        gl_lds16(pAl + kb, sAl + tid * 8);
        gl_lds16(pAl + kb + rstep, sAl + 2048 + tid * 8);
        gl_lds16(pBh + kb, sBh + tid * 8);
        gl_lds16(pBh + kb + rstep, sBh + 2048 + tid * 8);
        gl_lds16(pBl + kb, sBl + tid * 8);
        gl_lds16(pBl + kb + rstep, sBl + 2048 + tid * 8);
        __syncthreads();

        bhalf8 fah[4], fal[4], fbh[4], fbl[4];
#pragma unroll
        for (int i = 0; i < 4; i++) {
            fah[i] = *(const bhalf8*)(sAh + (wm + i * 16 + l15) * 32 + quad * 8);
            fal[i] = *(const bhalf8*)(sAl + (wm + i * 16 + l15) * 32 + quad * 8);
            fbh[i] = *(const bhalf8*)(sBh + (wn + i * 16 + l15) * 32 + quad * 8);
            fbl[i] = *(const bhalf8*)(sBl + (wn + i * 16 + l15) * 32 + quad * 8);
        }
#pragma unroll
        for (int i = 0; i < 4; i++)
#pragma unroll
            for (int j = 0; j < 4; j++) {
                acc[i][j] = __builtin_amdgcn_mfma_f32_16x16x32_bf16(fah[i], fbh[j], acc[i][j], 0, 0, 0);
                acc[i][j] = __builtin_amdgcn_mfma_f32_16x16x32_bf16(fah[i], fbl[j], acc[i][j], 0, 0, 0);
                acc[i][j] = __builtin_amdgcn_mfma_f32_16x16x32_bf16(fal[i], fbh[j], acc[i][j], 0, 0, 0);
            }
        __syncthreads();
    }

#pragma unroll
    for (int j = 0; j < 4; j++) {
        int col = blockN + wn + j * 16 + l15;
#pragma unroll
        for (int i = 0; i < 4; i++)
#pragma unroll
            for (int r = 0; r < 4; r++) {
                size_t row = blockM + wm + i * 16 + quad * 4 + r;
                C[row * ldc + col] = f2bf(acc[i][j][r]);
            }
    }
}

// ---------------------------------------------------------------------------
// gemm2: C_f32[M][256] = A_bf16 @ (Bh+Bl)^T + bias, 2-term (A already bf16).
// ---------------------------------------------------------------------------
__global__ __launch_bounds__(256) void gemm_bf2(const unsigned short* __restrict__ A,
                                                const unsigned short* __restrict__ Bh,
                                                const unsigned short* __restrict__ Bl,
                                                float* __restrict__ C,
                                                const float* __restrict__ bias) {
    const int K = 256;
    __shared__ unsigned short sA[4096];
    __shared__ unsigned short sBh[4096];
    __shared__ unsigned short sBl[4096];

    const int tid = threadIdx.x;
    const int nb = blockIdx.x & 1;
    const int mb = blockIdx.x >> 1;
    const size_t blockM = (size_t)mb * 128;
    const int blockN = nb * 128;

    const int srow = tid >> 2;
    const int schunk = (tid & 3) * 8;
    const unsigned short* pA = A + (blockM + srow) * K + schunk;
    const unsigned short* pBh = Bh + (size_t)(blockN + srow) * K + schunk;
    const unsigned short* pBl = Bl + (size_t)(blockN + srow) * K + schunk;
    const size_t rstep = (size_t)64 * K;

    const int w = tid >> 6;
    const int lane = tid & 63;
    const int quad = lane >> 4;
    const int l15 = lane & 15;
    const int wm = (w & 1) * 64;
    const int wn = (w >> 1) * 64;

    f32x4 acc[4][4];
#pragma unroll
    for (int i = 0; i < 4; i++)
#pragma unroll
        for (int j = 0; j < 4; j++) acc[i][j] = (f32x4){0.f, 0.f, 0.f, 0.f};

    for (int kb = 0; kb < K; kb += 32) {
        gl_lds16(pA + kb, sA + tid * 8);
        gl_lds16(pA + kb + rstep, sA + 2048 + tid * 8);
        gl_lds16(pBh + kb, sBh + tid * 8);
        gl_lds16(pBh + kb + rstep, sBh + 2048 + tid * 8);
        gl_lds16(pBl + kb, sBl + tid * 8);
        gl_lds16(pBl + kb + rstep, sBl + 2048 + tid * 8);
        __syncthreads();

        bhalf8 fa[4], fbh[4], fbl[4];
#pragma unroll
        for (int i = 0; i < 4; i++) {
            fa[i]  = *(const bhalf8*)(sA  + (wm + i * 16 + l15) * 32 + quad * 8);
            fbh[i] = *(const bhalf8*)(sBh + (wn + i * 16 + l15) * 32 + quad * 8);
            fbl[i] = *(const bhalf8*)(sBl + (wn + i * 16 + l15) * 32 + quad * 8);
        }
#pragma unroll
        for (int i = 0; i < 4; i++)
#pragma unroll
            for (int j = 0; j < 4; j++) {
                acc[i][j] = __builtin_amdgcn_mfma_f32_16x16x32_bf16(fa[i], fbh[j], acc[i][j], 0, 0, 0);
                acc[i][j] = __builtin_amdgcn_mfma_f32_16x16x32_bf16(fa[i], fbl[j], acc[i][j], 0, 0, 0);
            }
        __syncthreads();
    }

#pragma unroll
    for (int j = 0; j < 4; j++) {
        int col = blockN + wn + j * 16 + l15;
        float bv = bias[col];
#pragma unroll
        for (int i = 0; i < 4; i++)
#pragma unroll
            for (int r = 0; r < 4; r++) {
                size_t row = blockM + wm + i * 16 + quad * 4 + r;
                C[row * 256 + col] = acc[i][j][r] + bv;
            }
    }
}

// ---------------------------------------------------------------------------
// MFMA window attention, bf16 qkv in / bf16 attb out (structure validated R2).
// SCALE applied to scores post-MFMA (exact).
// ---------------------------------------------------------------------------
__global__ __launch_bounds__(256) void attn_mfma(const unsigned short* __restrict__ qkvb,
                                                 const float* __restrict__ T2,
                                                 unsigned short* __restrict__ attb) {
    __shared__ unsigned short Ks[256][40];    // [key][d]
    __shared__ unsigned short Vt[32][264];    // [d][key]
    __shared__ unsigned short Pc[4][16][40];  // per-wave P chunk

    const int tid = threadIdx.x;
    const int wi = blockIdx.x;   // b*64 + window
    const int h = blockIdx.y;    // 0..3
    const int br = blockIdx.z;   // 0..1
    const int logW = br ? 3 : 5;
    const int Wsp = 1 << logW;
    const int Hsp = 256 >> logW;
    const int logNWx = br ? 4 : 2;
    const int b = wi >> 6;
    const int win = wi & 63;
    const int wy = win >> logNWx;
    const int wx = win & ((1 << logNWx) - 1);
    const int ccol = br * 128 + h * 32;

#pragma unroll
    for (int it = 0; it < 8; ++it) {
        int n = it * 32 + (tid >> 3);
        int d4 = (tid & 7) * 4;
        int iy = n >> logW, ix = n & (Wsp - 1);
        size_t row = ((size_t)b * LL + (wy * Hsp + iy) * WW + wx * Wsp + ix) * 768;
        ushort4 kv = *(const ushort4*)(qkvb + row + 256 + ccol + d4);
        ushort4 vv = *(const ushort4*)(qkvb + row + 512 + ccol + d4);
        *(ushort4*)&Ks[n][d4] = kv;
        Vt[d4 + 0][n] = vv.x;
        Vt[d4 + 1][n] = vv.y;
        Vt[d4 + 2][n] = vv.z;
        Vt[d4 + 3][n] = vv.w;
    }
    __syncthreads();

    const int w = tid >> 6;
    const int lane = tid & 63;
    const int quad = lane >> 4;
    const int l15 = lane & 15;
    const f32x4 zero = {0.f, 0.f, 0.f, 0.f};

#pragma unroll 1
    for (int qt = 0; qt < 4; ++qt) {
        const int qbase = qt * 64 + w * 16;
        const int qrow = qbase + l15;
        const int iyq = qrow >> logW, ixq = qrow & (Wsp - 1);
        const size_t qpix = (size_t)b * LL + (wy * Hsp + iyq) * WW + wx * Wsp + ixq;
        bhalf8 qfrag = *(const bhalf8*)(qkvb + qpix * 768 + ccol + quad * 8);

        const float* Tb = T2 + (((size_t)(br * 4 + h) * 256) + (qbase + quad * 4)) * 256 + l15;

        f32x4 o0 = zero, o1 = zero;
        float rsum[4] = {0.f, 0.f, 0.f, 0.f};

#pragma unroll 2
        for (int kc = 0; kc < 8; ++kc) {
            const int kb0 = kc * 32;
            bhalf8 kf0 = *(const bhalf8*)&Ks[kb0 + l15][quad * 8];
            bhalf8 kf1 = *(const bhalf8*)&Ks[kb0 + 16 + l15][quad * 8];
            f32x4 s0 = __builtin_amdgcn_mfma_f32_16x16x32_bf16(qfrag, kf0, zero, 0, 0, 0);
            f32x4 s1 = __builtin_amdgcn_mfma_f32_16x16x32_bf16(qfrag, kf1, zero, 0, 0, 0);
#pragma unroll
            for (int i = 0; i < 4; ++i) {
                float p0 = __expf(fmaf(s0[i], SCALE, Tb[(size_t)i * 256 + kb0]));
                float p1 = __expf(fmaf(s1[i], SCALE, Tb[(size_t)i * 256 + kb0 + 16]));
                rsum[i] += p0 + p1;
                Pc[w][quad * 4 + i][l15] = f2bf(p0);
                Pc[w][quad * 4 + i][16 + l15] = f2bf(p1);
            }
            bhalf8 pf = *(const bhalf8*)&Pc[w][l15][quad * 8];
            bhalf8 vf0 = *(const bhalf8*)&Vt[l15][kb0 + quad * 8];
            bhalf8 vf1 = *(const bhalf8*)&Vt[16 + l15][kb0 + quad * 8];
            o0 = __builtin_amdgcn_mfma_f32_16x16x32_bf16(pf, vf0, o0, 0, 0, 0);
            o1 = __builtin_amdgcn_mfma_f32_16x16x32_bf16(pf, vf1, o1, 0, 0, 0);
        }

#pragma unroll
        for (int i = 0; i < 4; ++i) {
            float s = rsum[i];
            s += __shfl_xor(s, 1, 64);
            s += __shfl_xor(s, 2, 64);
            s += __shfl_xor(s, 4, 64);
            s += __shfl_xor(s, 8, 64);
            rsum[i] = 1.0f / s;
        }

#pragma unroll
        for (int i = 0; i < 4; ++i) {
            int r = qbase + quad * 4 + i;
            int iyr = r >> logW, ixr = r & (Wsp - 1);
            size_t pix = (size_t)b * LL + (wy * Hsp + iyr) * WW + wx * Wsp + ixr;
            unsigned short* op = attb + pix * 256 + ccol;
            op[l15] = f2bf(o0[i] * rsum[i]);
            op[16 + l15] = f2bf(o1[i] * rsum[i]);
        }
    }
}

// ---------------------------------------------------------------------------
// LePE: depthwise 3x3 on bf16 V, += (with bias) into bf16 attb (RMW).
// ---------------------------------------------------------------------------
__global__ __launch_bounds__(256) void lepe_kernel(const unsigned short* __restrict__ qkvb,
                                                   const float* __restrict__ w_dw,
                                                   const float* __restrict__ b_dw,
                                                   unsigned short* __restrict__ attb) {
    const int tid = threadIdx.x;
    const int c4 = (tid & 63) * 4;
    const int pix = blockIdx.x * 4 + (tid >> 6);
    const int bb = pix >> 14;
    const int y = (pix >> 7) & 127;
    const int x = pix & 127;

    float wreg[36];
    const float* wp = w_dw + c4 * 9;
#pragma unroll
    for (int q = 0; q < 9; q++) {
        float4 t = *(const float4*)(wp + q * 4);
        wreg[q * 4 + 0] = t.x; wreg[q * 4 + 1] = t.y;
        wreg[q * 4 + 2] = t.z; wreg[q * 4 + 3] = t.w;
    }

    float4 bv = *(const float4*)(b_dw + c4);
    ushort4 av = *(const ushort4*)(attb + ((size_t)pix << 8) + c4);
    float4 acc;
    acc.x = b2f(av.x) + bv.x; acc.y = b2f(av.y) + bv.y;
    acc.z = b2f(av.z) + bv.z; acc.w = b2f(av.w) + bv.w;

#pragma unroll
    for (int ky = 0; ky < 3; ky++) {
        int yy = y + ky - 1;
        if (yy < 0 || yy > 127) continue;
#pragma unroll
        for (int kx = 0; kx < 3; kx++) {
            int xx = x + kx - 1;
            if (xx < 0 || xx > 127) continue;
            int j = ky * 3 + kx;
            ushort4 v = *(const ushort4*)(qkvb + (((size_t)bb << 14) + yy * 128 + xx) * 768 + 512 + c4);
            acc.x = fmaf(b2f(v.x), wreg[0 * 9 + j], acc.x);
            acc.y = fmaf(b2f(v.y), wreg[1 * 9 + j], acc.y);
            acc.z = fmaf(b2f(v.z), wreg[2 * 9 + j], acc.z);
            acc.w = fmaf(b2f(v.w), wreg[3 * 9 + j], acc.w);
        }
    }
    ushort4 r;
    r.x = f2bf(acc.x); r.y = f2bf(acc.y); r.z = f2bf(acc.z); r.w = f2bf(acc.w);
    *(ushort4*)(attb + ((size_t)pix << 8) + c4) = r;
}

// ---------------------------------------------------------------------------
extern "C" void kernel_launch(void* const* d_in, const int* in_sizes, int n_in,
                              void* d_out, int out_size, void* d_ws, size_t ws_size,
                              hipStream_t stream) {
    const float* x     = (const float*)d_in[0];
    const float* w_qkv = (const float*)d_in[1];
    const float* w_proj= (const float*)d_in[2];
    const float* b_proj= (const float*)d_in[3];
    const float* w_dw  = (const float*)d_in[4];
    const float* b_dw  = (const float*)d_in[5];
    const float* pp_w  = (const float*)d_in[6];
    const float* pp_b  = (const float*)d_in[7];
    const float* ln1_g = (const float*)d_in[8];
    const float* ln1_b = (const float*)d_in[9];
    const float* l1_w  = (const float*)d_in[10];
    const float* l1_b  = (const float*)d_in[11];
    const float* ln2_g = (const float*)d_in[12];
    const float* ln2_b = (const float*)d_in[13];
    const float* l2_w  = (const float*)d_in[14];
    const float* l2_b  = (const float*)d_in[15];
    const float* ln3_g = (const float*)d_in[16];
    const float* ln3_b = (const float*)d_in[17];
    const float* l3_w  = (const float*)d_in[18];
    const float* l3_b  = (const float*)d_in[19];

    // Workspace layout, total ~195.0 MiB (same as passing R3-R5 footprint):
    float* pos = (float*)d_ws;                               // 7,680 f
    float* T2  = pos + 7680;                                 // 524,288 f
    unsigned short* qkvb = (unsigned short*)(T2 + 524288);   // 65536*768 sh (96 MiB)
    unsigned short* attb = qkvb + (size_t)NROWS * 768;       // 65536*256 sh (32 MiB)
    unsigned short* xh   = attb + (size_t)NROWS * 256;       // 32 MiB
    unsigned short* xl   = xh + (size_t)NROWS * 256;         // 32 MiB
    unsigned short* wqh  = xl + (size_t)NROWS * 256;         // 196,608 sh
    unsigned short* wql  = wqh + 768 * 256;
    unsigned short* wph  = wql + 768 * 256;                  // 65,536 sh
    unsigned short* wpl  = wph + 256 * 256;

    pos_kernel<<<2, 128, 0, stream>>>(pp_w, pp_b, ln1_g, ln1_b, l1_w, l1_b,
                                      ln2_g, ln2_b, l2_w, l2_b, ln3_g, ln3_b,
                                      l3_w, l3_b, pos);
    rpb_kernel<<<dim3(256, 4, 2), 256, 0, stream>>>(pos, T2);
    convw_kernel<<<768, 256, 0, stream>>>(w_qkv, wqh, wql, 256, 768);
    convw_kernel<<<256, 256, 0, stream>>>(w_proj, wph, wpl, 256, 256);
    convx_kernel<<<NROWS / 4, 256, 0, stream>>>(x, xh, xl);
    // qkv_bf16 = x @ w_qkv   (3-term split-bf16, global_load_lds staging)
    gemm_bf3<<<(NROWS / 128) * 6, 256, 0, stream>>>(xh, xl, wqh, wql, qkvb, 768, 6);
    // window attention -> attb (bf16)
    attn_mfma<<<dim3(256, 4, 2), 256, 0, stream>>>(qkvb, T2, attb);
    // LePE += depthwise conv on V (bf16 RMW)
    lepe_kernel<<<(B_ * LL) / 4, 256, 0, stream>>>(qkvb, w_dw, b_dw, attb);
    // d_out = attb @ w_proj + b_proj  (2-term, fp32 out, direct to d_out)
    gemm_bf2<<<(NROWS / 128) * 2, 256, 0, stream>>>(attb, wph, wpl, (float*)d_out, b_proj);
}